// Round 6
// baseline (487.621 us; speedup 1.0000x reference)
//
#include <hip/hip_runtime.h>
#include <hip/hip_bf16.h>
#include <hip/hip_cooperative_groups.h>

namespace cg = cooperative_groups;

typedef __hip_bfloat16 bf16;
typedef __attribute__((ext_vector_type(8))) short short8;
typedef __attribute__((ext_vector_type(4))) float f32x4;

#define F_BIAS 1
#define F_RELU 2
#define F_RES  4

__device__ __forceinline__ void st_out(float* p, float v){ *p = v; }
__device__ __forceinline__ void st_out(bf16* p, float v){ *p = __float2bfloat16(v); }
__device__ __forceinline__ short f2bs(float f){
  bf16 h = __float2bfloat16(f);
  return *reinterpret_cast<short*>(&h);
}

// async global->LDS, 16 B per lane.
__device__ __forceinline__ void gl_lds16(const void* g, void* l){
  __builtin_amdgcn_global_load_lds(
      (const __attribute__((address_space(1))) void*)g,
      (__attribute__((address_space(3))) void*)l, 16, 0, 0);
}

// LDS-only barrier: orders ds ops, leaves global_load_lds (vmcnt) in flight.
__device__ __forceinline__ void lgkm_barrier(){
  asm volatile("s_waitcnt lgkmcnt(0)" ::: "memory");
  __builtin_amdgcn_s_barrier();
}

// ---------------- prologue: weight prep + LN(x_T) + LN(x_S) ----------------
struct ProArgs {
  const float* wsrc[10];
  bf16* wdst[10];
  const float *xT, *xS, *tl1w, *tl1b, *sl1w, *sl1b;
  bf16 *hT, *hS;
};

template<int RL>
__device__ __forceinline__ void wave_ln(bf16* __restrict__ dst,
    const float* __restrict__ src, const float* __restrict__ w,
    const float* __restrict__ bvec, int row){
  int lane = threadIdx.x & 63;
  const float* s = src + (size_t)row*RL;
  float4 v0 = *(const float4*)(s + lane*4);
  float4 v1 = {0.f,0.f,0.f,0.f};
  float sum = v0.x+v0.y+v0.z+v0.w;
  float sq  = v0.x*v0.x+v0.y*v0.y+v0.z*v0.z+v0.w*v0.w;
  if (RL == 512){
    v1 = *(const float4*)(s + 256 + lane*4);
    sum += v1.x+v1.y+v1.z+v1.w;
    sq  += v1.x*v1.x+v1.y*v1.y+v1.z*v1.z+v1.w*v1.w;
  }
  #pragma unroll
  for (int off=32; off; off>>=1){
    sum += __shfl_xor(sum, off, 64);
    sq  += __shfl_xor(sq , off, 64);
  }
  const float inv = 1.0f/(float)RL;
  float mean = sum*inv;
  float rstd = rsqrtf(sq*inv - mean*mean + 1e-6f);
  float4 w0 = *(const float4*)(w + lane*4);
  float4 b0 = *(const float4*)(bvec + lane*4);
  bf16* d = dst + (size_t)row*RL;
  short4 o;
  o.x = f2bs((v0.x-mean)*rstd*w0.x + b0.x);
  o.y = f2bs((v0.y-mean)*rstd*w0.y + b0.y);
  o.z = f2bs((v0.z-mean)*rstd*w0.z + b0.z);
  o.w = f2bs((v0.w-mean)*rstd*w0.w + b0.w);
  *(short4*)((short*)d + lane*4) = o;
  if (RL == 512){
    float4 w1 = *(const float4*)(w + 256 + lane*4);
    float4 b1 = *(const float4*)(bvec + 256 + lane*4);
    short4 o1;
    o1.x = f2bs((v1.x-mean)*rstd*w1.x + b1.x);
    o1.y = f2bs((v1.y-mean)*rstd*w1.y + b1.y);
    o1.z = f2bs((v1.z-mean)*rstd*w1.z + b1.z);
    o1.w = f2bs((v1.w-mean)*rstd*w1.w + b1.w);
    *(short4*)((short*)d + 256 + lane*4) = o1;
  }
}

__global__ __launch_bounds__(256) void prologue(ProArgs a){
  int blk = blockIdx.x;
  int wid = threadIdx.x >> 6;
  if (blk < 1792){
    int v = blk*256 + threadIdx.x;
    int e = v*4;
    int seg = (e>=65536)+(e>=131072)+(e>=196608)+(e>=262144)+(e>=524288)
            + (e>=786432)+(e>=1048576)+(e>=1310720)+(e>=1572864);
    const int starts[10] = {0,65536,131072,196608,262144,524288,786432,
                            1048576,1310720,1572864};
    int off = e - starts[seg];
    float4 f = *(const float4*)(a.wsrc[seg] + off);
    short4 o;
    o.x = f2bs(f.x); o.y = f2bs(f.y); o.z = f2bs(f.z); o.w = f2bs(f.w);
    *(short4*)((short*)a.wdst[seg] + off) = o;
  } else if (blk < 1792 + 2048){
    wave_ln<256>(a.hT, a.xT, a.tl1w, a.tl1b, (blk-1792)*4 + wid);
  } else {
    wave_ln<512>(a.hS, a.xS, a.sl1w, a.sl1b, (blk-3840)*4 + wid);
  }
}

// -- MFMA bf16 GEMM body (256 thr): dbuf, barrier at TOP, used by gemm_dual --
template<int BM, int BN, int BK>
__device__ __forceinline__ void gemm_body(
    short* __restrict__ AsB, short* __restrict__ BsB,
    const bf16* __restrict__ A, const bf16* __restrict__ B,
    float* __restrict__ outF, bf16* __restrict__ outB,
    const float* __restrict__ bias, const float* __restrict__ resid,
    int K, int lda, int ldb, int ldc, int flags, int m0, int n0){
  int tid = threadIdx.x;
  int w = tid>>6, lane = tid&63, quad = lane>>4, l16 = lane&15;
  constexpr int MF  = BM/32;
  constexpr int NF  = BN/32;
  constexpr int CPR = BK/8;
  constexpr int CA  = BM*CPR/256;
  constexpr int CB  = BN*CPR/256;
  int wm = (w>>1)*(BM/2), wn = (w&1)*(BN/2);
  f32x4 acc[MF][NF];
  #pragma unroll
  for (int r=0;r<MF;r++)
    #pragma unroll
    for (int j=0;j<NF;j++)
      acc[r][j] = (f32x4){0.f,0.f,0.f,0.f};

  auto stage = [&](int k0, int half){
    short* as = AsB + half*(BM*BK);
    short* bs = BsB + half*(BN*BK);
    #pragma unroll
    for (int c=0;c<CA;c++){
      int ch = tid + c*256;
      int row = ch / CPR, p = ch % CPR;
      gl_lds16(A + (size_t)(m0+row)*lda + k0 + ((p ^ (row&(CPR-1)))*8),
               &as[row*BK + p*8]);
    }
    #pragma unroll
    for (int c=0;c<CB;c++){
      int ch = tid + c*256;
      int row = ch / CPR, p = ch % CPR;
      gl_lds16(B + (size_t)(n0+row)*ldb + k0 + ((p ^ (row&(CPR-1)))*8),
               &bs[row*BK + p*8]);
    }
  };

  stage(0, 0);
  int nk = K / BK;
  for (int t = 0; t < nk; ++t){
    __syncthreads();
    if (t+1 < nk) stage((t+1)*BK, (t+1)&1);
    const short* as = AsB + (t&1)*(BM*BK);
    const short* bs = BsB + (t&1)*(BN*BK);
    #pragma unroll
    for (int ks=0; ks<BK/32; ++ks){
      short8 af[MF], bfr[NF];
      #pragma unroll
      for (int r=0;r<MF;r++){
        int rr = wm + r*16 + l16;
        af[r] = *(short8*)&as[rr*BK + (((ks*4+quad) ^ (rr&(CPR-1)))*8)];
      }
      #pragma unroll
      for (int j=0;j<NF;j++){
        int rr = wn + j*16 + l16;
        bfr[j] = *(short8*)&bs[rr*BK + (((ks*4+quad) ^ (rr&(CPR-1)))*8)];
      }
      #pragma unroll
      for (int r=0;r<MF;r++)
        #pragma unroll
        for (int j=0;j<NF;j++)
          acc[r][j] = __builtin_amdgcn_mfma_f32_16x16x32_bf16(af[r], bfr[j], acc[r][j], 0,0,0);
    }
  }
  #pragma unroll
  for (int r=0;r<MF;r++){
    int mb = m0 + wm + r*16 + quad*4;
    #pragma unroll
    for (int j=0;j<NF;j++){
      int n = n0 + wn + j*16 + l16;
      float bv = (flags & F_BIAS) ? bias[n] : 0.0f;
      #pragma unroll
      for (int e=0;e<4;e++){
        float v = acc[r][j][e] + bv;
        if (flags & F_RELU) v = fmaxf(v, 0.0f);
        long long idx = (long long)(mb+e)*ldc + n;
        if (flags & F_RES) v += resid[idx];
        if (outF) outF[idx] = v;
        if (outB) st_out(outB + idx, v);
      }
    }
  }
}

// ---- dual GEMM: two independent <64,128> GEMMs in one launch (1-D grid) ----
struct GArgs {
  const bf16 *A, *B;
  float* outF; bf16* outB;
  const float *bias, *resid;
  int K, lda, ldb, ldc, flags, ty;
};
__global__ __launch_bounds__(256) void gemm_dual(GArgs g0, GArgs g1, int n0){
  __shared__ __align__(16) short As[2*64*64];
  __shared__ __align__(16) short Bs[2*128*64];
  int id = blockIdx.x;
  bool first = id < n0;
  const GArgs& g = first ? g0 : g1;
  int t = first ? id : id - n0;
  int bx = t / g.ty, by = t - bx*g.ty;
  gemm_body<64,128,64>(As, Bs, g.A, g.B, g.outF, g.outB, g.bias, g.resid,
                       g.K, g.lda, g.ldb, g.ldc, g.flags, bx*64, by*128);
}

// -- 512-thread MFMA GEMM body (8 waves: 2M x 4N), dbuf, barrier at TOP -----
template<int BM, int BN, int BK>
__device__ __forceinline__ void gemm512_body(
    short* __restrict__ AsB, short* __restrict__ BsB,
    const bf16* __restrict__ A, const bf16* __restrict__ B,
    float* __restrict__ outF, bf16* __restrict__ outB,
    const float* __restrict__ bias, const float* __restrict__ resid,
    int K, int lda, int ldb, int ldc, int flags, int m0, int n0){
  int tid = threadIdx.x;
  int w = tid>>6, lane = tid&63, quad = lane>>4, l16 = lane&15;
  constexpr int MF  = BM/32;         // per-wave M fragments (BM/2 rows /16)
  constexpr int NF  = BN/64;         // per-wave N fragments (BN/4 cols /16)
  constexpr int CPR = BK/8;
  constexpr int CA  = BM*CPR/512;
  constexpr int CB  = BN*CPR/512;
  int wm = (w>>2)*(BM/2), wn = (w&3)*(BN/4);
  f32x4 acc[MF][NF];
  #pragma unroll
  for (int r=0;r<MF;r++)
    #pragma unroll
    for (int j=0;j<NF;j++)
      acc[r][j] = (f32x4){0.f,0.f,0.f,0.f};

  auto stage = [&](int k0, int half){
    short* as = AsB + half*(BM*BK);
    short* bs = BsB + half*(BN*BK);
    #pragma unroll
    for (int c=0;c<CA;c++){
      int ch = tid + c*512;
      int row = ch / CPR, p = ch % CPR;
      gl_lds16(A + (size_t)(m0+row)*lda + k0 + ((p ^ (row&(CPR-1)))*8),
               &as[row*BK + p*8]);
    }
    #pragma unroll
    for (int c=0;c<CB;c++){
      int ch = tid + c*512;
      int row = ch / CPR, p = ch % CPR;
      gl_lds16(B + (size_t)(n0+row)*ldb + k0 + ((p ^ (row&(CPR-1)))*8),
               &bs[row*BK + p*8]);
    }
  };

  stage(0, 0);
  int nk = K / BK;
  for (int t = 0; t < nk; ++t){
    __syncthreads();
    if (t+1 < nk) stage((t+1)*BK, (t+1)&1);
    const short* as = AsB + (t&1)*(BM*BK);
    const short* bs = BsB + (t&1)*(BN*BK);
    #pragma unroll
    for (int ks=0; ks<BK/32; ++ks){
      short8 af[MF], bfr[NF];
      #pragma unroll
      for (int r=0;r<MF;r++){
        int rr = wm + r*16 + l16;
        af[r] = *(short8*)&as[rr*BK + (((ks*4+quad) ^ (rr&(CPR-1)))*8)];
      }
      #pragma unroll
      for (int j=0;j<NF;j++){
        int rr = wn + j*16 + l16;
        bfr[j] = *(short8*)&bs[rr*BK + (((ks*4+quad) ^ (rr&(CPR-1)))*8)];
      }
      #pragma unroll
      for (int r=0;r<MF;r++)
        #pragma unroll
        for (int j=0;j<NF;j++)
          acc[r][j] = __builtin_amdgcn_mfma_f32_16x16x32_bf16(af[r], bfr[j], acc[r][j], 0,0,0);
    }
  }
  #pragma unroll
  for (int r=0;r<MF;r++){
    int mb = m0 + wm + r*16 + quad*4;
    #pragma unroll
    for (int j=0;j<NF;j++){
      int n = n0 + wn + j*16 + l16;
      float bv = (flags & F_BIAS) ? bias[n] : 0.0f;
      #pragma unroll
      for (int e=0;e<4;e++){
        float v = acc[r][j][e] + bv;
        if (flags & F_RELU) v = fmaxf(v, 0.0f);
        long long idx = (long long)(mb+e)*ldc + n;
        if (flags & F_RES) v += resid[idx];
        if (outF) outF[idx] = v;
        if (outB) st_out(outB + idx, v);
      }
    }
  }
}

// -- MFMA GEMM + fused row-LN epilogue (BM=32, N=ldc=256, BK=64, 512 thr) ---
__device__ void gemm_ln_body(short* arena, float (*redS)[32], float (*redQ)[32],
    const bf16* __restrict__ A, const bf16* __restrict__ B,
    float* __restrict__ outF, bf16* __restrict__ outLN,
    const float* __restrict__ resid,
    const float* __restrict__ lnw, const float* __restrict__ lnb,
    int K, int lda, int ldb, int flags, int m0,
    long long obase, long long rbase){
  short* As = arena;           // 2*32*64   = 4096 shorts
  short* Bs = arena + 4096;    // 2*256*64  = 32768 shorts
  int tid = threadIdx.x;
  int w = tid>>6, lane = tid&63, quad = lane>>4, l16 = lane&15;
  int wm = (w>>2)*16;
  int wn = (w&3)*64;
  f32x4 acc[4];
  #pragma unroll
  for (int j=0;j<4;j++) acc[j] = (f32x4){0.f,0.f,0.f,0.f};

  auto stage = [&](int k0, int half){
    short* as = As + half*(32*64);
    short* bs = Bs + half*(256*64);
    if (tid < 256){
      int row = tid >> 3, p = tid & 7;
      gl_lds16(A + (size_t)(m0+row)*lda + k0 + ((p ^ (row&7))*8),
               &as[row*64 + p*8]);
    }
    #pragma unroll
    for (int c=0;c<4;c++){
      int ch = tid + c*512;
      int row = ch >> 3, p = ch & 7;
      gl_lds16(B + (size_t)row*ldb + k0 + ((p ^ (row&7))*8),
               &bs[row*64 + p*8]);
    }
  };

  stage(0, 0);
  int nk = K / 64;
  for (int t = 0; t < nk; ++t){
    __syncthreads();
    if (t+1 < nk) stage((t+1)*64, (t+1)&1);
    const short* as = As + (t&1)*(32*64);
    const short* bs = Bs + (t&1)*(256*64);
    #pragma unroll
    for (int ks=0; ks<2; ++ks){
      int rr = wm + l16;
      short8 af = *(short8*)&as[rr*64 + (((ks*4+quad) ^ (rr&7))*8)];
      #pragma unroll
      for (int j=0;j<4;j++){
        int rb = wn + j*16 + l16;
        short8 bfr = *(short8*)&bs[rb*64 + (((ks*4+quad) ^ (rb&7))*8)];
        acc[j] = __builtin_amdgcn_mfma_f32_16x16x32_bf16(af, bfr, acc[j], 0,0,0);
      }
    }
  }
  #pragma unroll
  for (int e=0;e<4;e++){
    int row = wm + quad*4 + e;
    float s = 0.f, q2 = 0.f;
    #pragma unroll
    for (int j=0;j<4;j++){
      float v = acc[j][e];
      if (flags & F_RES)
        v += resid[rbase + (long long)(m0+row)*256 + wn + j*16 + l16];
      acc[j][e] = v;
      s += v; q2 += v*v;
    }
    #pragma unroll
    for (int off=1; off<16; off<<=1){
      s  += __shfl_xor(s , off, 16);
      q2 += __shfl_xor(q2, off, 16);
    }
    if (l16==0){ redS[w&3][row] = s; redQ[w&3][row] = q2; }
  }
  __syncthreads();
  #pragma unroll
  for (int e=0;e<4;e++){
    int row = wm + quad*4 + e;
    float tot = redS[0][row] + redS[1][row] + redS[2][row] + redS[3][row];
    float tq  = redQ[0][row] + redQ[1][row] + redQ[2][row] + redQ[3][row];
    float mean = tot * (1.0f/256.0f);
    float var  = tq * (1.0f/256.0f) - mean*mean;
    float rstd = rsqrtf(var + 1e-6f);
    #pragma unroll
    for (int j=0;j<4;j++){
      int col = wn + j*16 + l16;
      float v = acc[j][e];
      long long idx = obase + (long long)(m0+row)*256 + col;
      if (outF) outF[idx] = v;
      outLN[idx] = __float2bfloat16((v-mean)*rstd*lnw[col] + lnb[col]);
    }
  }
}

// ------- 512-thread fused spatial attention (dbuf full-K, 8-wave) ----------
__device__ void spatial512(short* arena, float (*redM)[32], float (*redS2)[32],
                           const bf16* __restrict__ qk,
                           float* __restrict__ out1, bf16* __restrict__ swB,
                           int ct, int b){
  bf16* Qall = (bf16*)arena;                 // 16*512 = 8192 elems (16KB)
  bf16* KsB  = (bf16*)(arena + 8192);        // 2 x 256*64 (2x32KB)
  int tid = threadIdx.x;
  int w = tid>>6, lane = tid&63, quad = lane>>4, l16 = lane&15;
  const bf16* qbase = qk + ((size_t)(b*256 + ct*16))*1024;
  #pragma unroll
  for (int c=0;c<2;c++){
    int ch = tid + c*512;
    int row = ch>>6, p = ch&63;
    gl_lds16(qbase + (size_t)row*1024 + ((p ^ (row&7))*8), &Qall[row*512 + p*8]);
  }
  auto stageK = [&](int h, int half){
    bf16* ks = KsB + half*(256*64);
    #pragma unroll
    for (int c=0;c<4;c++){
      int ch = tid + c*512;
      int e = ch>>3, p = ch&7;
      gl_lds16(qk + ((size_t)(b*256 + e))*1024 + 512 + h*64 + ((p ^ (e&7))*8),
               &ks[e*64 + p*8]);
    }
  };
  stageK(0, 0);
  float fRes[2][4];
  #pragma unroll
  for (int j=0;j<2;j++)
    #pragma unroll
    for (int e=0;e<4;e++) fRes[j][e] = 0.0f;

  for (int h=0; h<8; ++h){
    __syncthreads();                   // drain stageK(h) (+Qall at h=0)
    if (h+1 < 8) stageK(h+1, (h+1)&1); // in flight across whole head compute
    const bf16* kcur = KsB + (h&1)*(256*64);
    f32x4 acc[2];
    acc[0] = (f32x4){0.f,0.f,0.f,0.f};
    acc[1] = (f32x4){0.f,0.f,0.f,0.f};
    #pragma unroll
    for (int ki=0; ki<2; ++ki){
      int g = h*8 + ki*4 + quad;
      short8 aq = *(short8*)&Qall[l16*512 + ((g ^ (l16&7))*8)];
      #pragma unroll
      for (int j=0;j<2;j++){
        int e = w*32 + j*16 + l16;
        short8 bk = *(short8*)&kcur[e*64 + (((ki*4+quad) ^ (e&7))*8)];
        acc[j] = __builtin_amdgcn_mfma_f32_16x16x32_bf16(aq, bk, acc[j], 0,0,0);
      }
    }
    #pragma unroll
    for (int e=0;e<4;e++){
      float s0 = acc[0][e]*0.125f, s1 = acc[1][e]*0.125f;
      acc[0][e] = s0; acc[1][e] = s1;
      float m = fmaxf(s0, s1);
      #pragma unroll
      for (int off=1; off<16; off<<=1) m = fmaxf(m, __shfl_xor(m, off, 16));
      if (l16==0) redM[w][quad*4+e] = m;
    }
    lgkm_barrier();                    // orders redM; K prefetch stays in flight
    #pragma unroll
    for (int e=0;e<4;e++){
      int r = quad*4+e;
      float m = redM[0][r];
      #pragma unroll
      for (int ww=1; ww<8; ww++) m = fmaxf(m, redM[ww][r]);
      float s = 0.0f;
      #pragma unroll
      for (int j=0;j<2;j++){
        float p = __expf(acc[j][e]-m);
        acc[j][e] = p; s += p;
      }
      #pragma unroll
      for (int off=1; off<16; off<<=1) s += __shfl_xor(s, off, 16);
      if (l16==0) redS2[w][r] = s;
    }
    lgkm_barrier();
    #pragma unroll
    for (int e=0;e<4;e++){
      int r = quad*4+e;
      float tot = 0.0f;
      #pragma unroll
      for (int ww=0; ww<8; ww++) tot += redS2[ww][r];
      float inv = 0.125f/tot;
      #pragma unroll
      for (int j=0;j<2;j++) fRes[j][e] += acc[j][e]*inv;
    }
  }
  #pragma unroll
  for (int e=0;e<4;e++){
    int c = ct*16 + quad*4 + e;
    size_t rb = ((size_t)b*256 + c)*256;
    #pragma unroll
    for (int j=0;j<2;j++){
      int col = w*32 + j*16 + l16;
      out1[rb+col] = fRes[j][e];
      swB[rb+col]  = __float2bfloat16(fRes[j][e]);
    }
  }
}

// ---------------- MFMA flash temporal causal attention ----------------
__device__ __forceinline__ int fsw(int row){ return (row>>1)&3; }
__global__ __launch_bounds__(256) void flash_mfma(
    const bf16* __restrict__ qkv, bf16* __restrict__ o){
  int qt = (int)gridDim.x - 1 - (int)blockIdx.x;   // longest blocks first
  int h = blockIdx.y, b = blockIdx.z;
  int tid = threadIdx.x;
  int w = tid>>6, lane = tid&63, quad = lane>>4, l16 = lane&15;
  __shared__ __align__(16) bf16 Qs[64*32];
  __shared__ __align__(16) bf16 Ks[2][64*32];
  __shared__ __align__(16) bf16 Vt[2][32*72];
  __shared__ __align__(16) bf16 Ps[64*72];
  const bf16* base = qkv + (size_t)b*512*768;
  int t0 = qt*64;
  int srow = tid>>2, spos = tid&3;
  gl_lds16(base + (size_t)(t0+srow)*768 + h*32 + ((spos ^ fsw(srow))*8),
           &Qs[srow*32 + spos*8]);
  {
    const bf16* rp = base + (size_t)srow*768 + h*32;
    gl_lds16(rp + 256 + ((spos ^ fsw(srow))*8), &Ks[0][srow*32 + spos*8]);
    short8 v = *(const short8*)(rp + 512 + spos*8);
    #pragma unroll
    for (int q=0;q<8;q++){
      short tmp = v[q];
      Vt[0][(spos*8+q)*72 + srow] = *(bf16*)&tmp;
    }
  }
  f32x4 accO[2];
  accO[0] = (f32x4){0.f,0.f,0.f,0.f};
  accO[1] = (f32x4){0.f,0.f,0.f,0.f};
  float m_i[4], l_i[4];
  #pragma unroll
  for (int e=0;e<4;e++){ m_i[e] = -3.0e38f; l_i[e] = 0.0f; }
  const float scale = 0.17677669529663687f;
  __syncthreads();
  int rq = w*16 + l16;
  short8 aq = *(short8*)&Qs[rq*32 + ((quad ^ fsw(rq))*8)];

  for (int kt = 0; kt <= qt; ++kt){
    if (kt) __syncthreads();
    int cur = kt&1, nxt = cur^1;
    bool pre = (kt < qt);
    short8 vpre;
    if (pre){
      const bf16* rp = base + (size_t)((kt+1)*64 + srow)*768 + h*32;
      gl_lds16(rp + 256 + ((spos ^ fsw(srow))*8), &Ks[nxt][srow*32 + spos*8]);
      vpre = *(const short8*)(rp + 512 + spos*8);
    }
    f32x4 S[4];
    #pragma unroll
    for (int j2=0;j2<4;j2++){
      int rk = j2*16 + l16;
      short8 bk = *(short8*)&Ks[cur][rk*32 + ((quad ^ fsw(rk))*8)];
      S[j2] = __builtin_amdgcn_mfma_f32_16x16x32_bf16(aq, bk,
                (f32x4){0.f,0.f,0.f,0.f}, 0,0,0);
    }
    bool diag = (kt == qt);
    int s0 = kt*64;
    int qrow_base = t0 + w*16 + quad*4;
    #pragma unroll
    for (int e=0;e<4;e++){
      float sv[4];
      #pragma unroll
      for (int j2=0;j2<4;j2++){
        float x = S[j2][e]*scale;
        if (diag && (s0 + j2*16 + l16 > qrow_base + e)) x = -3.0e38f;
        sv[j2] = x;
      }
      float mx = fmaxf(fmaxf(sv[0],sv[1]), fmaxf(sv[2],sv[3]));
      #pragma unroll
      for (int off=1; off<16; off<<=1) mx = fmaxf(mx, __shfl_xor(mx, off, 64));
      float m_new = fmaxf(m_i[e], mx);
      float alpha = __expf(m_i[e]-m_new);
      float rs = 0.0f;
      #pragma unroll
      for (int j2=0;j2<4;j2++){
        float p = __expf(sv[j2]-m_new);
        rs += p;
        Ps[(w*16+quad*4+e)*72 + j2*16 + l16] = __float2bfloat16(p);
      }
      #pragma unroll
      for (int off=1; off<16; off<<=1) rs += __shfl_xor(rs, off, 64);
      l_i[e] = l_i[e]*alpha + rs;
      m_i[e] = m_new;
      accO[0][e] *= alpha;
      accO[1][e] *= alpha;
    }
    asm volatile("s_waitcnt lgkmcnt(0)" ::: "memory");
    __builtin_amdgcn_sched_barrier(0);
    #pragma unroll
    for (int sh=0; sh<2; ++sh){
      short8 ap = *(short8*)&Ps[(w*16+l16)*72 + sh*32 + quad*8];
      #pragma unroll
      for (int dh=0; dh<2; ++dh){
        short8 bv = *(short8*)&Vt[cur][(dh*16+l16)*72 + sh*32 + quad*8];
        accO[dh] = __builtin_amdgcn_mfma_f32_16x16x32_bf16(ap, bv, accO[dh], 0,0,0);
      }
    }
    if (pre){
      #pragma unroll
      for (int q=0;q<8;q++){
        short tmp = vpre[q];
        Vt[nxt][(spos*8+q)*72 + srow] = *(bf16*)&tmp;
      }
    }
  }
  #pragma unroll
  for (int e=0;e<4;e++){
    float inv = 1.0f/l_i[e];
    int t = t0 + w*16 + quad*4 + e;
    bf16* op = o + ((size_t)(b*512+t))*256 + h*32 + l16;
    op[0]  = __float2bfloat16(accO[0][e]*inv);
    op[16] = __float2bfloat16(accO[1][e]*inv);
  }
}

// ------------- mega cooperative kernel: spatial + steps 5..10 --------------
struct MegaArgs {
  const bf16 *qk; float* out1; bf16* swB;
  const bf16 *bufOb, *Wob; float* bufX; bf16* bufHb; const float* xT;
  const float *tl2w, *tl2b;
  const bf16 *f1w1b; bf16* bufBigB; const float* f1b1;
  const bf16 *f1w2b; float* bufTO; bf16* bufTOb; const float* f1b2;
  float* bufX2; const float *flw, *flb;
  const bf16 *f2w1b; const float* f2b1;
  const bf16 *f2w2b; float* out0; const float* f2b2;
};

__global__ __launch_bounds__(512) void mega(MegaArgs a){
  __shared__ __align__(16) short arena[40960];   // 80 KB
  __shared__ float redA[8][32], redB[8][32];
  cg::grid_group grid = cg::this_grid();
  int blk = blockIdx.x;

  // S0: fused spatial attention (needs qkB from gemm_dual)
  spatial512(arena, redA, redB, a.qk, a.out1, a.swB, blk & 15, blk >> 4);
  grid.sync();

  // S1: x = o @ Wo^T + x_T ; h2 = LN(x)
  gemm_ln_body(arena, redA, redB, a.bufOb, a.Wob, a.bufX, a.bufHb, a.xT,
               a.tl2w, a.tl2b, 256, 256, 256, F_RES, blk*32, 0, 0);
  grid.sync();

  // S2: f1 = relu(h2 @ w1^T + b1)  (1024 tiles, 4 per block)
  for (int i=0;i<4;i++){
    int t = blk + i*256;
    gemm512_body<64,128,64>(arena, arena + 8192, a.bufHb, a.f1w1b,
        nullptr, a.bufBigB, a.f1b1, nullptr,
        256, 256, 256, 1024, F_BIAS|F_RELU, (t>>3)*64, (t&7)*128);
  }
  grid.sync();

  // S3: TO = f1 @ w2^T + b2 + x
  gemm512_body<64,128,64>(arena, arena + 8192, a.bufBigB, a.f1w2b,
      a.bufTO, a.bufTOb, a.f1b2, a.bufX,
      1024, 1024, 1024, 256, F_BIAS|F_RES, (blk>>1)*64, (blk&1)*128);
  grid.sync();

  // S4: x2 = TO @ sw[b]^T + TO ; h3 = LN(x2)  (batched over b)
  {
    int bz = blk >> 4, bx = blk & 15;
    gemm_ln_body(arena, redA, redB,
        a.bufTOb + (size_t)bz*131072, a.swB + (size_t)bz*65536,
        a.bufX2, a.bufHb, a.bufTO, a.flw, a.flb,
        256, 256, 256, F_RES, bx*32,
        (long long)bz*131072, (long long)bz*131072);
  }
  grid.sync();

  // S5: f2 hidden  (1024 tiles, 4 per block)
  for (int i=0;i<4;i++){
    int t = blk + i*256;
    gemm512_body<64,128,64>(arena, arena + 8192, a.bufHb, a.f2w1b,
        nullptr, a.bufBigB, a.f2b1, nullptr,
        256, 256, 256, 1024, F_BIAS|F_RELU, (t>>3)*64, (t&7)*128);
  }
  grid.sync();

  // S6: out = f2 @ w2^T + b2 + x2 -> fp32 d_out
  gemm512_body<64,128,64>(arena, arena + 8192, a.bufBigB, a.f2w2b,
      a.out0, (bf16*)nullptr, a.f2b2, a.bufX2,
      1024, 1024, 1024, 256, F_BIAS|F_RES, (blk>>1)*64, (blk&1)*128);
}

extern "C" void kernel_launch(void* const* d_in, const int* in_sizes, int n_in,
                              void* d_out, int out_size, void* d_ws, size_t ws_size,
                              hipStream_t stream){
  (void)in_sizes; (void)n_in; (void)out_size; (void)ws_size;
  const float* x_T  = (const float*)d_in[0];
  const float* x_S  = (const float*)d_in[1];
  const float* Wq_t = (const float*)d_in[2];
  const float* Wk_t = (const float*)d_in[3];
  const float* Wv_t = (const float*)d_in[4];
  const float* Wo   = (const float*)d_in[5];
  const float* Wq_s = (const float*)d_in[6];
  const float* Wk_s = (const float*)d_in[7];
  const float* f1w1 = (const float*)d_in[8];
  const float* f1b1 = (const float*)d_in[9];
  const float* f1w2 = (const float*)d_in[10];
  const float* f1b2 = (const float*)d_in[11];
  const float* f2w1 = (const float*)d_in[12];
  const float* f2b1 = (const float*)d_in[13];
  const float* f2w2 = (const float*)d_in[14];
  const float* f2b2 = (const float*)d_in[15];
  const float* tl1w = (const float*)d_in[16];
  const float* tl1b = (const float*)d_in[17];
  const float* tl2w = (const float*)d_in[18];
  const float* tl2b = (const float*)d_in[19];
  const float* sl1w = (const float*)d_in[20];
  const float* sl1b = (const float*)d_in[21];
  const float* flw  = (const float*)d_in[22];
  const float* flb  = (const float*)d_in[23];

  float* ws = (float*)d_ws;
  size_t off = 0;
  bf16*  Wqkvb  = (bf16*)(ws + off); off += 768*256/2;
  bf16*  Wob    = (bf16*)(ws + off); off += 256*256/2;
  bf16*  f1w1b  = (bf16*)(ws + off); off += 1024*256/2;
  bf16*  f1w2b  = (bf16*)(ws + off); off += 256*1024/2;
  bf16*  f2w1b  = (bf16*)(ws + off); off += 1024*256/2;
  bf16*  f2w2b  = (bf16*)(ws + off); off += 256*1024/2;
  bf16*  WSb    = (bf16*)(ws + off); off += 1024*512/2;
  bf16*  bufHb  = (bf16*)(ws + off); off += (size_t)8192*256/2;
  bf16*  bufHSb = (bf16*)(ws + off); off += (size_t)4096*512/2;
  bf16*  bufQKVb= (bf16*)(ws + off); off += (size_t)8192*768/2;
  bf16*  bufBigB= (bf16*)(ws + off); off += (size_t)8192*1024/2;
  bf16*  bufOb  = (bf16*)(ws + off); off += (size_t)8192*256/2;
  bf16*  bufTOb = (bf16*)(ws + off); off += (size_t)8192*256/2;
  bf16*  swB    = (bf16*)(ws + off); off += (size_t)16*256*256/2;
  bf16*  qkB    = (bf16*)(ws + off); off += (size_t)4096*1024/2;
  float* bufX   = ws + off; off += (size_t)8192*256;
  float* bufTO  = ws + off; off += (size_t)8192*256;
  float* bufX2  = ws + off; off += (size_t)8192*256;

  float* out0 = (float*)d_out;                      // [B,T,C]
  float* out1 = out0 + (size_t)16*512*256;          // spatial_weights [B,C,C]

  // 1. prologue: weight prep + LN(x_T) + LN(x_S)
  ProArgs pa;
  pa.wsrc[0]=Wq_t;  pa.wdst[0]=Wqkvb;
  pa.wsrc[1]=Wk_t;  pa.wdst[1]=Wqkvb+65536;
  pa.wsrc[2]=Wv_t;  pa.wdst[2]=Wqkvb+131072;
  pa.wsrc[3]=Wo;    pa.wdst[3]=Wob;
  pa.wsrc[4]=f1w1;  pa.wdst[4]=f1w1b;
  pa.wsrc[5]=f1w2;  pa.wdst[5]=f1w2b;
  pa.wsrc[6]=f2w1;  pa.wdst[6]=f2w1b;
  pa.wsrc[7]=f2w2;  pa.wdst[7]=f2w2b;
  pa.wsrc[8]=Wq_s;  pa.wdst[8]=WSb;
  pa.wsrc[9]=Wk_s;  pa.wdst[9]=WSb+262144;
  pa.xT=x_T; pa.xS=x_S; pa.tl1w=tl1w; pa.tl1b=tl1b;
  pa.sl1w=sl1w; pa.sl1b=sl1b; pa.hT=bufHb; pa.hS=bufHSb;
  prologue<<<4864,256,0,stream>>>(pa);

  // 2. dual: qkv (768 tiles) + spatial projection (512 tiles)
  GArgs gq, gs;
  gq.A=bufHb;  gq.B=Wqkvb; gq.outF=nullptr; gq.outB=bufQKVb;
  gq.bias=nullptr; gq.resid=nullptr;
  gq.K=256; gq.lda=256; gq.ldb=256; gq.ldc=768; gq.flags=0; gq.ty=6;
  gs.A=bufHSb; gs.B=WSb;   gs.outF=nullptr; gs.outB=qkB;
  gs.bias=nullptr; gs.resid=nullptr;
  gs.K=512; gs.lda=512; gs.ldb=512; gs.ldc=1024; gs.flags=0; gs.ty=8;
  gemm_dual<<<1280,256,0,stream>>>(gq, gs, 768);

  // 3. temporal causal flash attention -> bf16 o
  flash_mfma<<<dim3(8,8,16),256,0,stream>>>(bufQKVb, bufOb);

  // 4. cooperative mega: spatial + {LN-GEMM, FFN1, fuse, LN-GEMM, FFN2, out}
  MegaArgs ma;
  ma.qk=qkB; ma.out1=out1; ma.swB=swB;
  ma.bufOb=bufOb; ma.Wob=Wob; ma.bufX=bufX; ma.bufHb=bufHb; ma.xT=x_T;
  ma.tl2w=tl2w; ma.tl2b=tl2b;
  ma.f1w1b=f1w1b; ma.bufBigB=bufBigB; ma.f1b1=f1b1;
  ma.f1w2b=f1w2b; ma.bufTO=bufTO; ma.bufTOb=bufTOb; ma.f1b2=f1b2;
  ma.bufX2=bufX2; ma.flw=flw; ma.flb=flb;
  ma.f2w1b=f2w1b; ma.f2b1=f2b1;
  ma.f2w2b=f2w2b; ma.out0=out0; ma.f2b2=f2b2;
  void* kargs[] = { (void*)&ma };
  hipLaunchCooperativeKernel((const void*)mega, dim3(256), dim3(512),
                             kargs, 0, stream);
}

// Round 7
// 294.195 us; speedup vs baseline: 1.6575x; 1.6575x over previous
//
#include <hip/hip_runtime.h>
#include <hip/hip_bf16.h>

typedef __hip_bfloat16 bf16;
typedef __attribute__((ext_vector_type(8))) short short8;
typedef __attribute__((ext_vector_type(4))) float f32x4;

#define F_BIAS 1
#define F_RELU 2
#define F_RES  4

__device__ __forceinline__ void st_out(float* p, float v){ *p = v; }
__device__ __forceinline__ void st_out(bf16* p, float v){ *p = __float2bfloat16(v); }
__device__ __forceinline__ short f2bs(float f){
  bf16 h = __float2bfloat16(f);
  return *reinterpret_cast<short*>(&h);
}

// async global->LDS, 16 B per lane (linear LDS dest, pre-swizzled global src).
__device__ __forceinline__ void gl_lds16(const void* g, void* l){
  __builtin_amdgcn_global_load_lds(
      (const __attribute__((address_space(1))) void*)g,
      (__attribute__((address_space(3))) void*)l, 16, 0, 0);
}

// LDS-only barrier: orders ds ops, leaves global_load_lds (vmcnt) in flight.
__device__ __forceinline__ void lgkm_barrier(){
  asm volatile("s_waitcnt lgkmcnt(0)" ::: "memory");
  __builtin_amdgcn_s_barrier();
}

// ---------------- prologue: weight prep + LN(x_T) + LN(x_S) ----------------
struct ProArgs {
  const float* wsrc[10];
  bf16* wdst[10];
  const float *xT, *xS, *tl1w, *tl1b, *sl1w, *sl1b;
  bf16 *hT, *hS;
};

template<int RL>
__device__ __forceinline__ void wave_ln(bf16* __restrict__ dst,
    const float* __restrict__ src, const float* __restrict__ w,
    const float* __restrict__ bvec, int row){
  int lane = threadIdx.x & 63;
  const float* s = src + (size_t)row*RL;
  float4 v0 = *(const float4*)(s + lane*4);
  float4 v1 = {0.f,0.f,0.f,0.f};
  float sum = v0.x+v0.y+v0.z+v0.w;
  float sq  = v0.x*v0.x+v0.y*v0.y+v0.z*v0.z+v0.w*v0.w;
  if (RL == 512){
    v1 = *(const float4*)(s + 256 + lane*4);
    sum += v1.x+v1.y+v1.z+v1.w;
    sq  += v1.x*v1.x+v1.y*v1.y+v1.z*v1.z+v1.w*v1.w;
  }
  #pragma unroll
  for (int off=32; off; off>>=1){
    sum += __shfl_xor(sum, off, 64);
    sq  += __shfl_xor(sq , off, 64);
  }
  const float inv = 1.0f/(float)RL;
  float mean = sum*inv;
  float rstd = rsqrtf(sq*inv - mean*mean + 1e-6f);
  float4 w0 = *(const float4*)(w + lane*4);
  float4 b0 = *(const float4*)(bvec + lane*4);
  bf16* d = dst + (size_t)row*RL;
  short4 o;
  o.x = f2bs((v0.x-mean)*rstd*w0.x + b0.x);
  o.y = f2bs((v0.y-mean)*rstd*w0.y + b0.y);
  o.z = f2bs((v0.z-mean)*rstd*w0.z + b0.z);
  o.w = f2bs((v0.w-mean)*rstd*w0.w + b0.w);
  *(short4*)((short*)d + lane*4) = o;
  if (RL == 512){
    float4 w1 = *(const float4*)(w + 256 + lane*4);
    float4 b1 = *(const float4*)(bvec + 256 + lane*4);
    short4 o1;
    o1.x = f2bs((v1.x-mean)*rstd*w1.x + b1.x);
    o1.y = f2bs((v1.y-mean)*rstd*w1.y + b1.y);
    o1.z = f2bs((v1.z-mean)*rstd*w1.z + b1.z);
    o1.w = f2bs((v1.w-mean)*rstd*w1.w + b1.w);
    *(short4*)((short*)d + 256 + lane*4) = o1;
  }
}

__global__ __launch_bounds__(256) void prologue(ProArgs a){
  int blk = blockIdx.x;
  int wid = threadIdx.x >> 6;
  if (blk < 1792){
    int v = blk*256 + threadIdx.x;
    int e = v*4;
    int seg = (e>=65536)+(e>=131072)+(e>=196608)+(e>=262144)+(e>=524288)
            + (e>=786432)+(e>=1048576)+(e>=1310720)+(e>=1572864);
    const int starts[10] = {0,65536,131072,196608,262144,524288,786432,
                            1048576,1310720,1572864};
    int off = e - starts[seg];
    float4 f = *(const float4*)(a.wsrc[seg] + off);
    short4 o;
    o.x = f2bs(f.x); o.y = f2bs(f.y); o.z = f2bs(f.z); o.w = f2bs(f.w);
    *(short4*)((short*)a.wdst[seg] + off) = o;
  } else if (blk < 1792 + 2048){
    wave_ln<256>(a.hT, a.xT, a.tl1w, a.tl1b, (blk-1792)*4 + wid);
  } else {
    wave_ln<512>(a.hS, a.xS, a.sl1w, a.sl1b, (blk-3840)*4 + wid);
  }
}

// -- MFMA bf16 GEMM body (256 thr): dbuf, barrier at TOP (gemm_dual only) ---
template<int BM, int BN, int BK>
__device__ __forceinline__ void gemm_body(
    short* __restrict__ AsB, short* __restrict__ BsB,
    const bf16* __restrict__ A, const bf16* __restrict__ B,
    float* __restrict__ outF, bf16* __restrict__ outB,
    const float* __restrict__ bias, const float* __restrict__ resid,
    int K, int lda, int ldb, int ldc, int flags, int m0, int n0){
  int tid = threadIdx.x;
  int w = tid>>6, lane = tid&63, quad = lane>>4, l16 = lane&15;
  constexpr int MF  = BM/32;
  constexpr int NF  = BN/32;
  constexpr int CPR = BK/8;
  constexpr int CA  = BM*CPR/256;
  constexpr int CB  = BN*CPR/256;
  int wm = (w>>1)*(BM/2), wn = (w&1)*(BN/2);
  f32x4 acc[MF][NF];
  #pragma unroll
  for (int r=0;r<MF;r++)
    #pragma unroll
    for (int j=0;j<NF;j++)
      acc[r][j] = (f32x4){0.f,0.f,0.f,0.f};

  auto stage = [&](int k0, int half){
    short* as = AsB + half*(BM*BK);
    short* bs = BsB + half*(BN*BK);
    #pragma unroll
    for (int c=0;c<CA;c++){
      int ch = tid + c*256;
      int row = ch / CPR, p = ch % CPR;
      gl_lds16(A + (size_t)(m0+row)*lda + k0 + ((p ^ (row&(CPR-1)))*8),
               &as[row*BK + p*8]);
    }
    #pragma unroll
    for (int c=0;c<CB;c++){
      int ch = tid + c*256;
      int row = ch / CPR, p = ch % CPR;
      gl_lds16(B + (size_t)(n0+row)*ldb + k0 + ((p ^ (row&(CPR-1)))*8),
               &bs[row*BK + p*8]);
    }
  };

  stage(0, 0);
  int nk = K / BK;
  for (int t = 0; t < nk; ++t){
    __syncthreads();
    if (t+1 < nk) stage((t+1)*BK, (t+1)&1);
    const short* as = AsB + (t&1)*(BM*BK);
    const short* bs = BsB + (t&1)*(BN*BK);
    #pragma unroll
    for (int ks=0; ks<BK/32; ++ks){
      short8 af[MF], bfr[NF];
      #pragma unroll
      for (int r=0;r<MF;r++){
        int rr = wm + r*16 + l16;
        af[r] = *(short8*)&as[rr*BK + (((ks*4+quad) ^ (rr&(CPR-1)))*8)];
      }
      #pragma unroll
      for (int j=0;j<NF;j++){
        int rr = wn + j*16 + l16;
        bfr[j] = *(short8*)&bs[rr*BK + (((ks*4+quad) ^ (rr&(CPR-1)))*8)];
      }
      #pragma unroll
      for (int r=0;r<MF;r++)
        #pragma unroll
        for (int j=0;j<NF;j++)
          acc[r][j] = __builtin_amdgcn_mfma_f32_16x16x32_bf16(af[r], bfr[j], acc[r][j], 0,0,0);
    }
  }
  #pragma unroll
  for (int r=0;r<MF;r++){
    int mb = m0 + wm + r*16 + quad*4;
    #pragma unroll
    for (int j=0;j<NF;j++){
      int n = n0 + wn + j*16 + l16;
      float bv = (flags & F_BIAS) ? bias[n] : 0.0f;
      #pragma unroll
      for (int e=0;e<4;e++){
        float v = acc[r][j][e] + bv;
        if (flags & F_RELU) v = fmaxf(v, 0.0f);
        long long idx = (long long)(mb+e)*ldc + n;
        if (flags & F_RES) v += resid[idx];
        if (outF) outF[idx] = v;
        if (outB) st_out(outB + idx, v);
      }
    }
  }
}

// ---- dual GEMM: two independent <64,128> GEMMs in one launch (1-D grid) ----
struct GArgs {
  const bf16 *A, *B;
  float* outF; bf16* outB;
  const float *bias, *resid;
  int K, lda, ldb, ldc, flags, ty;
};
__global__ __launch_bounds__(256) void gemm_dual(GArgs g0, GArgs g1, int n0){
  __shared__ __align__(16) short As[2*64*64];
  __shared__ __align__(16) short Bs[2*128*64];
  int id = blockIdx.x;
  bool first = id < n0;
  const GArgs& g = first ? g0 : g1;
  int t = first ? id : id - n0;
  int bx = t / g.ty, by = t - bx*g.ty;
  gemm_body<64,128,64>(As, Bs, g.A, g.B, g.outF, g.outB, g.bias, g.resid,
                       g.K, g.lda, g.ldb, g.ldc, g.flags, bx*64, by*128);
}

// -- MFMA GEMM + fused row-LN epilogue (BM=32, N=ldc=256, BK=64, 512 thr) ---
__global__ __launch_bounds__(512) void gemm_ln(
    const bf16* __restrict__ A, const bf16* __restrict__ B,
    float* __restrict__ outF, bf16* __restrict__ outLN,
    const float* __restrict__ resid,
    const float* __restrict__ lnw, const float* __restrict__ lnb,
    int K, int lda, int ldb, int flags,
    long long sA, long long sB, long long sO, long long sR){
  int bz = blockIdx.z;
  A += (size_t)bz*sA;
  B += (size_t)bz*sB;
  long long obase = (long long)bz*sO;
  __shared__ __align__(16) short As[2*32*64];
  __shared__ __align__(16) short Bs[2*256*64];
  __shared__ float redS[4][32], redQ[4][32];
  int tid = threadIdx.x;
  int m0 = blockIdx.x*32;
  int w = tid>>6, lane = tid&63, quad = lane>>4, l16 = lane&15;
  int wm = (w>>2)*16;
  int wn = (w&3)*64;
  f32x4 acc[4];
  #pragma unroll
  for (int j=0;j<4;j++) acc[j] = (f32x4){0.f,0.f,0.f,0.f};

  auto stage = [&](int k0, int half){
    short* as = As + half*(32*64);
    short* bs = Bs + half*(256*64);
    if (tid < 256){
      int row = tid >> 3, p = tid & 7;
      gl_lds16(A + (size_t)(m0+row)*lda + k0 + ((p ^ (row&7))*8),
               &as[row*64 + p*8]);
    }
    #pragma unroll
    for (int c=0;c<4;c++){
      int ch = tid + c*512;
      int row = ch >> 3, p = ch & 7;
      gl_lds16(B + (size_t)row*ldb + k0 + ((p ^ (row&7))*8),
               &bs[row*64 + p*8]);
    }
  };

  stage(0, 0);
  int nk = K / 64;
  for (int t = 0; t < nk; ++t){
    __syncthreads();
    if (t+1 < nk) stage((t+1)*64, (t+1)&1);
    const short* as = As + (t&1)*(32*64);
    const short* bs = Bs + (t&1)*(256*64);
    #pragma unroll
    for (int ks=0; ks<2; ++ks){
      int rr = wm + l16;
      short8 af = *(short8*)&as[rr*64 + (((ks*4+quad) ^ (rr&7))*8)];
      #pragma unroll
      for (int j=0;j<4;j++){
        int rb = wn + j*16 + l16;
        short8 bfr = *(short8*)&bs[rb*64 + (((ks*4+quad) ^ (rb&7))*8)];
        acc[j] = __builtin_amdgcn_mfma_f32_16x16x32_bf16(af, bfr, acc[j], 0,0,0);
      }
    }
  }
  #pragma unroll
  for (int e=0;e<4;e++){
    int row = wm + quad*4 + e;
    float s = 0.f, q2 = 0.f;
    #pragma unroll
    for (int j=0;j<4;j++){
      float v = acc[j][e];
      if (flags & F_RES)
        v += resid[(long long)bz*sR + (long long)(m0+row)*256 + wn + j*16 + l16];
      acc[j][e] = v;
      s += v; q2 += v*v;
    }
    #pragma unroll
    for (int off=1; off<16; off<<=1){
      s  += __shfl_xor(s , off, 16);
      q2 += __shfl_xor(q2, off, 16);
    }
    if (l16==0){ redS[w&3][row] = s; redQ[w&3][row] = q2; }
  }
  __syncthreads();
  #pragma unroll
  for (int e=0;e<4;e++){
    int row = wm + quad*4 + e;
    float tot = redS[0][row] + redS[1][row] + redS[2][row] + redS[3][row];
    float tq  = redQ[0][row] + redQ[1][row] + redQ[2][row] + redQ[3][row];
    float mean = tot * (1.0f/256.0f);
    float var  = tq * (1.0f/256.0f) - mean*mean;
    float rstd = rsqrtf(var + 1e-6f);
    #pragma unroll
    for (int j=0;j<4;j++){
      int col = wn + j*16 + l16;
      float v = acc[j][e];
      long long idx = obase + (long long)(m0+row)*256 + col;
      if (outF) outF[idx] = v;
      outLN[idx] = __float2bfloat16((v-mean)*rstd*lnw[col] + lnb[col]);
    }
  }
}

// ---- fused FFN: TO = relu(A@W1^T + b1)@W2^T + b2 + resid, BM=32/block -----
// Phase A: H[32x1024] built in LDS (bf16, XOR-swizzled); phase B consumes it.
// No bufBig round-trip, no extra launch. 144 KB LDS -> 1 block/CU, 512 thr.
struct FfnArgs {
  const bf16 *A;        // [8192,256]
  const bf16 *W1;       // [1024,256]
  const float *B1;      // [1024]
  const bf16 *W2;       // [256,1024]
  const float *B2;      // [256]
  const float *resid;   // [8192,256] f32
  float *outF;          // [8192,256] f32
  bf16  *outB;          // optional bf16 mirror
};

__global__ __launch_bounds__(512) void ffn(FfnArgs a){
  __shared__ __align__(16) short Afull[32*256];    // 16 KB, staged once
  __shared__ __align__(16) short Hs[32*1024];      // 64 KB hidden (bf16)
  __shared__ __align__(16) short Bst[2*16384];     // 64 KB dbuf W-panel stage
  int tid = threadIdx.x;
  int w = tid>>6, lane = tid&63, quad = lane>>4, l16 = lane&15;
  int m0 = blockIdx.x*32;
  int wm  = (w>>2)*16;        // 0/16
  int wnA = (w&3)*32;         // phase A col block within 128-chunk
  int wnB = (w&3)*64;         // phase B col block within 256

  // stage Afull: rows 0..31, CPR=32, pre-swizzled src / linear dest
  #pragma unroll
  for (int c=0;c<2;c++){
    int ch = tid + c*512;
    int row = ch>>5, p = ch&31;
    gl_lds16(a.A + (size_t)(m0+row)*256 + ((p ^ row)*8), &Afull[ch*8]);
  }
  // phase A W1 chunk stage: iter i -> chunk nc=i>>2 (128 rows), kt=i&3
  auto stageA = [&](int i, int half){
    short* bs = Bst + half*16384;
    int nc = i>>2, kt = i&3;
    #pragma unroll
    for (int c=0;c<2;c++){
      int ch = tid + c*512;
      int row = ch>>3, p = ch&7;
      gl_lds16(a.W1 + (size_t)(nc*128+row)*256 + kt*64 + ((p ^ (row&7))*8),
               &bs[ch*8]);
    }
  };
  // phase B W2 stage: kt in 0..15 (256 rows x 64 k)
  auto stageB = [&](int kt, int half){
    short* bs = Bst + half*16384;
    #pragma unroll
    for (int c=0;c<4;c++){
      int ch = tid + c*512;
      int row = ch>>3, p = ch&7;
      gl_lds16(a.W2 + (size_t)row*1024 + kt*64 + ((p ^ (row&7))*8),
               &bs[ch*8]);
    }
  };

  stageA(0, 0);
  f32x4 acc[2];
  for (int i=0; i<32; ++i){
    __syncthreads();                       // drain stage i (+Afull at i=0)
    if (i+1 < 32) stageA(i+1, (i+1)&1);
    const short* bs = Bst + (i&1)*16384;
    int kt = i&3, nc = i>>2;
    if (kt==0){
      acc[0] = (f32x4){0.f,0.f,0.f,0.f};
      acc[1] = (f32x4){0.f,0.f,0.f,0.f};
    }
    #pragma unroll
    for (int ks=0; ks<2; ++ks){
      int rr = wm + l16;
      int kk = kt*8 + ks*4 + quad;         // 0..31
      short8 af = *(short8*)&Afull[rr*256 + ((kk ^ rr)*8)];
      #pragma unroll
      for (int j=0;j<2;j++){
        int rb = wnA + j*16 + l16;         // 0..127 local W1 row
        short8 bk = *(short8*)&bs[rb*64 + (((ks*4+quad) ^ (rb&7))*8)];
        acc[j] = __builtin_amdgcn_mfma_f32_16x16x32_bf16(af, bk, acc[j], 0,0,0);
      }
    }
    if (kt==3){
      // H chunk -> LDS (bf16, XOR-swizzled on k-group for phase-B reads)
      #pragma unroll
      for (int j=0;j<2;j++)
        #pragma unroll
        for (int e=0;e<4;e++){
          int row = wm + quad*4 + e;
          int col = nc*128 + wnA + j*16 + l16;
          float v = fmaxf(acc[j][e] + a.B1[col], 0.0f);
          int grp = col>>3;
          Hs[row*1024 + ((grp ^ (row&7))<<3) + (col&7)] = f2bs(v);
        }
    }
  }

  stageB(0, 0);                            // Bst[0] free (last read at i=30)
  __syncthreads();                         // transition: drains Hs writes + stage
  f32x4 accB[4];
  #pragma unroll
  for (int j=0;j<4;j++) accB[j] = (f32x4){0.f,0.f,0.f,0.f};
  for (int kt=0; kt<16; ++kt){
    if (kt) __syncthreads();
    if (kt+1 < 16) stageB(kt+1, (kt+1)&1);
    const short* bs = Bst + (kt&1)*16384;
    #pragma unroll
    for (int ks=0; ks<2; ++ks){
      int rr = wm + l16;
      int kk = kt*8 + ks*4 + quad;         // 0..127
      short8 af = *(short8*)&Hs[rr*1024 + ((kk ^ (rr&7))*8)];
      #pragma unroll
      for (int j=0;j<4;j++){
        int rb = wnB + j*16 + l16;         // 0..255 W2 row (output col)
        short8 bk = *(short8*)&bs[rb*64 + (((ks*4+quad) ^ (rb&7))*8)];
        accB[j] = __builtin_amdgcn_mfma_f32_16x16x32_bf16(af, bk, accB[j], 0,0,0);
      }
    }
  }
  #pragma unroll
  for (int j=0;j<4;j++){
    int n = wnB + j*16 + l16;
    float bv = a.B2[n];
    #pragma unroll
    for (int e=0;e<4;e++){
      int row = m0 + wm + quad*4 + e;
      long long idx = (long long)row*256 + n;
      float v = accB[j][e] + bv + a.resid[idx];
      a.outF[idx] = v;
      if (a.outB) st_out(a.outB + idx, v);
    }
  }
}

// ---------------- MFMA flash temporal causal attention ----------------
__device__ __forceinline__ int fsw(int row){ return (row>>1)&3; }
__global__ __launch_bounds__(256) void flash_mfma(
    const bf16* __restrict__ qkv, bf16* __restrict__ o){
  int qt = (int)gridDim.x - 1 - (int)blockIdx.x;   // longest blocks first
  int h = blockIdx.y, b = blockIdx.z;
  int tid = threadIdx.x;
  int w = tid>>6, lane = tid&63, quad = lane>>4, l16 = lane&15;
  __shared__ __align__(16) bf16 Qs[64*32];
  __shared__ __align__(16) bf16 Ks[2][64*32];
  __shared__ __align__(16) bf16 Vt[2][32*72];
  __shared__ __align__(16) bf16 Ps[64*72];
  const bf16* base = qkv + (size_t)b*512*768;
  int t0 = qt*64;
  int srow = tid>>2, spos = tid&3;
  gl_lds16(base + (size_t)(t0+srow)*768 + h*32 + ((spos ^ fsw(srow))*8),
           &Qs[srow*32 + spos*8]);
  {
    const bf16* rp = base + (size_t)srow*768 + h*32;
    gl_lds16(rp + 256 + ((spos ^ fsw(srow))*8), &Ks[0][srow*32 + spos*8]);
    short8 v = *(const short8*)(rp + 512 + spos*8);
    #pragma unroll
    for (int q=0;q<8;q++){
      short tmp = v[q];
      Vt[0][(spos*8+q)*72 + srow] = *(bf16*)&tmp;
    }
  }
  f32x4 accO[2];
  accO[0] = (f32x4){0.f,0.f,0.f,0.f};
  accO[1] = (f32x4){0.f,0.f,0.f,0.f};
  float m_i[4], l_i[4];
  #pragma unroll
  for (int e=0;e<4;e++){ m_i[e] = -3.0e38f; l_i[e] = 0.0f; }
  const float scale = 0.17677669529663687f;
  __syncthreads();
  int rq = w*16 + l16;
  short8 aq = *(short8*)&Qs[rq*32 + ((quad ^ fsw(rq))*8)];

  for (int kt = 0; kt <= qt; ++kt){
    if (kt) __syncthreads();
    int cur = kt&1, nxt = cur^1;
    bool pre = (kt < qt);
    short8 vpre;
    if (pre){
      const bf16* rp = base + (size_t)((kt+1)*64 + srow)*768 + h*32;
      gl_lds16(rp + 256 + ((spos ^ fsw(srow))*8), &Ks[nxt][srow*32 + spos*8]);
      vpre = *(const short8*)(rp + 512 + spos*8);
    }
    f32x4 S[4];
    #pragma unroll
    for (int j2=0;j2<4;j2++){
      int rk = j2*16 + l16;
      short8 bk = *(short8*)&Ks[cur][rk*32 + ((quad ^ fsw(rk))*8)];
      S[j2] = __builtin_amdgcn_mfma_f32_16x16x32_bf16(aq, bk,
                (f32x4){0.f,0.f,0.f,0.f}, 0,0,0);
    }
    bool diag = (kt == qt);
    int s0 = kt*64;
    int qrow_base = t0 + w*16 + quad*4;
    #pragma unroll
    for (int e=0;e<4;e++){
      float sv[4];
      #pragma unroll
      for (int j2=0;j2<4;j2++){
        float x = S[j2][e]*scale;
        if (diag && (s0 + j2*16 + l16 > qrow_base + e)) x = -3.0e38f;
        sv[j2] = x;
      }
      float mx = fmaxf(fmaxf(sv[0],sv[1]), fmaxf(sv[2],sv[3]));
      #pragma unroll
      for (int off=1; off<16; off<<=1) mx = fmaxf(mx, __shfl_xor(mx, off, 64));
      float m_new = fmaxf(m_i[e], mx);
      float alpha = __expf(m_i[e]-m_new);
      float rs = 0.0f;
      #pragma unroll
      for (int j2=0;j2<4;j2++){
        float p = __expf(sv[j2]-m_new);
        rs += p;
        Ps[(w*16+quad*4+e)*72 + j2*16 + l16] = __float2bfloat16(p);
      }
      #pragma unroll
      for (int off=1; off<16; off<<=1) rs += __shfl_xor(rs, off, 64);
      l_i[e] = l_i[e]*alpha + rs;
      m_i[e] = m_new;
      accO[0][e] *= alpha;
      accO[1][e] *= alpha;
    }
    asm volatile("s_waitcnt lgkmcnt(0)" ::: "memory");
    __builtin_amdgcn_sched_barrier(0);
    #pragma unroll
    for (int sh=0; sh<2; ++sh){
      short8 ap = *(short8*)&Ps[(w*16+l16)*72 + sh*32 + quad*8];
      #pragma unroll
      for (int dh=0; dh<2; ++dh){
        short8 bv = *(short8*)&Vt[cur][(dh*16+l16)*72 + sh*32 + quad*8];
        accO[dh] = __builtin_amdgcn_mfma_f32_16x16x32_bf16(ap, bv, accO[dh], 0,0,0);
      }
    }
    if (pre){
      #pragma unroll
      for (int q=0;q<8;q++){
        short tmp = vpre[q];
        Vt[nxt][(spos*8+q)*72 + srow] = *(bf16*)&tmp;
      }
    }
  }
  #pragma unroll
  for (int e=0;e<4;e++){
    float inv = 1.0f/l_i[e];
    int t = t0 + w*16 + quad*4 + e;
    bf16* op = o + ((size_t)(b*512+t))*256 + h*32 + l16;
    op[0]  = __float2bfloat16(accO[0][e]*inv);
    op[16] = __float2bfloat16(accO[1][e]*inv);
  }
}

// ------- standalone fused spatial attention (full-K dbuf, 256 thr) ---------
__global__ __launch_bounds__(256) void spatial_fused(
    const bf16* __restrict__ qk, float* __restrict__ out1,
    bf16* __restrict__ swB){
  int ct = blockIdx.x & 15, b = blockIdx.x >> 4;
  int tid = threadIdx.x;
  int w = tid>>6, lane = tid&63, quad = lane>>4, l16 = lane&15;
  __shared__ __align__(16) bf16 Qall[16*512];
  __shared__ __align__(16) bf16 Ks[2][256*64];
  __shared__ float redM[4][16], redS2[4][16];
  const bf16* qbase = qk + ((size_t)(b*256 + ct*16))*1024;
  #pragma unroll
  for (int c=0;c<4;c++){
    int ch = tid + c*256;
    int row = ch>>6, p = ch&63;
    gl_lds16(qbase + (size_t)row*1024 + ((p ^ (row&7))*8), &Qall[row*512 + p*8]);
  }
  auto stageK = [&](int h, int half){
    bf16* ks = Ks[half];
    #pragma unroll
    for (int c=0;c<8;c++){
      int ch = tid + c*256;
      int e = ch>>3, p = ch&7;
      gl_lds16(qk + ((size_t)(b*256 + e))*1024 + 512 + h*64 + ((p ^ (e&7))*8),
               &ks[e*64 + p*8]);
    }
  };
  stageK(0, 0);
  float fRes[4][4];
  #pragma unroll
  for (int j=0;j<4;j++)
    #pragma unroll
    for (int e=0;e<4;e++) fRes[j][e] = 0.0f;

  for (int h=0; h<8; ++h){
    __syncthreads();
    if (h+1 < 8) stageK(h+1, (h+1)&1);
    const bf16* kcur = Ks[h&1];
    f32x4 acc[4];
    #pragma unroll
    for (int j=0;j<4;j++) acc[j] = (f32x4){0.f,0.f,0.f,0.f};
    #pragma unroll
    for (int ki=0; ki<2; ++ki){
      int g = h*8 + ki*4 + quad;
      short8 aq = *(short8*)&Qall[l16*512 + ((g ^ (l16&7))*8)];
      #pragma unroll
      for (int j=0;j<4;j++){
        int e = w*64 + j*16 + l16;
        short8 bk = *(short8*)&kcur[e*64 + (((ki*4+quad) ^ (e&7))*8)];
        acc[j] = __builtin_amdgcn_mfma_f32_16x16x32_bf16(aq, bk, acc[j], 0,0,0);
      }
    }
    #pragma unroll
    for (int e=0;e<4;e++){
      float m = -3.0e38f;
      #pragma unroll
      for (int j=0;j<4;j++){
        float s = acc[j][e]*0.125f;
        acc[j][e] = s;
        m = fmaxf(m, s);
      }
      #pragma unroll
      for (int off=1; off<16; off<<=1) m = fmaxf(m, __shfl_xor(m, off, 16));
      if (l16==0) redM[w][quad*4+e] = m;
    }
    lgkm_barrier();
    #pragma unroll
    for (int e=0;e<4;e++){
      int r = quad*4+e;
      float m = fmaxf(fmaxf(redM[0][r],redM[1][r]), fmaxf(redM[2][r],redM[3][r]));
      float s = 0.0f;
      #pragma unroll
      for (int j=0;j<4;j++){
        float p = __expf(acc[j][e]-m);
        acc[j][e] = p; s += p;
      }
      #pragma unroll
      for (int off=1; off<16; off<<=1) s += __shfl_xor(s, off, 16);
      if (l16==0) redS2[w][r] = s;
    }
    lgkm_barrier();
    #pragma unroll
    for (int e=0;e<4;e++){
      int r = quad*4+e;
      float tot = redS2[0][r]+redS2[1][r]+redS2[2][r]+redS2[3][r];
      float inv = 0.125f/tot;
      #pragma unroll
      for (int j=0;j<4;j++) fRes[j][e] += acc[j][e]*inv;
    }
  }
  #pragma unroll
  for (int e=0;e<4;e++){
    int c = ct*16 + quad*4 + e;
    size_t rb = ((size_t)b*256 + c)*256;
    #pragma unroll
    for (int j=0;j<4;j++){
      int col = w*64 + j*16 + l16;
      out1[rb+col] = fRes[j][e];
      swB[rb+col]  = __float2bfloat16(fRes[j][e]);
    }
  }
}

extern "C" void kernel_launch(void* const* d_in, const int* in_sizes, int n_in,
                              void* d_out, int out_size, void* d_ws, size_t ws_size,
                              hipStream_t stream){
  (void)in_sizes; (void)n_in; (void)out_size; (void)ws_size;
  const float* x_T  = (const float*)d_in[0];
  const float* x_S  = (const float*)d_in[1];
  const float* Wq_t = (const float*)d_in[2];
  const float* Wk_t = (const float*)d_in[3];
  const float* Wv_t = (const float*)d_in[4];
  const float* Wo   = (const float*)d_in[5];
  const float* Wq_s = (const float*)d_in[6];
  const float* Wk_s = (const float*)d_in[7];
  const float* f1w1 = (const float*)d_in[8];
  const float* f1b1 = (const float*)d_in[9];
  const float* f1w2 = (const float*)d_in[10];
  const float* f1b2 = (const float*)d_in[11];
  const float* f2w1 = (const float*)d_in[12];
  const float* f2b1 = (const float*)d_in[13];
  const float* f2w2 = (const float*)d_in[14];
  const float* f2b2 = (const float*)d_in[15];
  const float* tl1w = (const float*)d_in[16];
  const float* tl1b = (const float*)d_in[17];
  const float* tl2w = (const float*)d_in[18];
  const float* tl2b = (const float*)d_in[19];
  const float* sl1w = (const float*)d_in[20];
  const float* sl1b = (const float*)d_in[21];
  const float* flw  = (const float*)d_in[22];
  const float* flb  = (const float*)d_in[23];

  float* ws = (float*)d_ws;
  size_t off = 0;
  bf16*  Wqkvb  = (bf16*)(ws + off); off += 768*256/2;
  bf16*  Wob    = (bf16*)(ws + off); off += 256*256/2;
  bf16*  f1w1b  = (bf16*)(ws + off); off += 1024*256/2;
  bf16*  f1w2b  = (bf16*)(ws + off); off += 256*1024/2;
  bf16*  f2w1b  = (bf16*)(ws + off); off += 1024*256/2;
  bf16*  f2w2b  = (bf16*)(ws + off); off += 256*1024/2;
  bf16*  WSb    = (bf16*)(ws + off); off += 1024*512/2;
  bf16*  bufHb  = (bf16*)(ws + off); off += (size_t)8192*256/2;
  bf16*  bufHSb = (bf16*)(ws + off); off += (size_t)4096*512/2;
  bf16*  bufQKVb= (bf16*)(ws + off); off += (size_t)8192*768/2;
  bf16*  bufOb  = (bf16*)(ws + off); off += (size_t)8192*256/2;
  bf16*  bufTOb = (bf16*)(ws + off); off += (size_t)8192*256/2;
  bf16*  swB    = (bf16*)(ws + off); off += (size_t)16*256*256/2;
  bf16*  qkB    = (bf16*)(ws + off); off += (size_t)4096*1024/2;
  float* bufX   = ws + off; off += (size_t)8192*256;
  float* bufTO  = ws + off; off += (size_t)8192*256;
  float* bufX2  = ws + off; off += (size_t)8192*256;

  float* out0 = (float*)d_out;                      // [B,T,C]
  float* out1 = out0 + (size_t)16*512*256;          // spatial_weights [B,C,C]

  // 1. prologue: weight prep + LN(x_T) + LN(x_S)
  ProArgs pa;
  pa.wsrc[0]=Wq_t;  pa.wdst[0]=Wqkvb;
  pa.wsrc[1]=Wk_t;  pa.wdst[1]=Wqkvb+65536;
  pa.wsrc[2]=Wv_t;  pa.wdst[2]=Wqkvb+131072;
  pa.wsrc[3]=Wo;    pa.wdst[3]=Wob;
  pa.wsrc[4]=f1w1;  pa.wdst[4]=f1w1b;
  pa.wsrc[5]=f1w2;  pa.wdst[5]=f1w2b;
  pa.wsrc[6]=f2w1;  pa.wdst[6]=f2w1b;
  pa.wsrc[7]=f2w2;  pa.wdst[7]=f2w2b;
  pa.wsrc[8]=Wq_s;  pa.wdst[8]=WSb;
  pa.wsrc[9]=Wk_s;  pa.wdst[9]=WSb+262144;
  pa.xT=x_T; pa.xS=x_S; pa.tl1w=tl1w; pa.tl1b=tl1b;
  pa.sl1w=sl1w; pa.sl1b=sl1b; pa.hT=bufHb; pa.hS=bufHSb;
  prologue<<<4864,256,0,stream>>>(pa);

  // 2. dual: qkv (768 tiles) + spatial projection (512 tiles)
  GArgs gq, gs;
  gq.A=bufHb;  gq.B=Wqkvb; gq.outF=nullptr; gq.outB=bufQKVb;
  gq.bias=nullptr; gq.resid=nullptr;
  gq.K=256; gq.lda=256; gq.ldb=256; gq.ldc=768; gq.flags=0; gq.ty=6;
  gs.A=bufHSb; gs.B=WSb;   gs.outF=nullptr; gs.outB=qkB;
  gs.bias=nullptr; gs.resid=nullptr;
  gs.K=512; gs.lda=512; gs.ldb=512; gs.ldc=1024; gs.flags=0; gs.ty=8;
  gemm_dual<<<1280,256,0,stream>>>(gq, gs, 768);

  // 3. standalone fused spatial attention (qkB L2-hot from step 2)
  spatial_fused<<<256,256,0,stream>>>(qkB, out1, swB);

  // 4. temporal causal flash attention -> bf16 o
  flash_mfma<<<dim3(8,8,16),256,0,stream>>>(bufQKVb, bufOb);
  // 5. x = o @ Wo^T + x_T ; h2 = LN(x)
  gemm_ln<<<dim3(256,1,1),512,0,stream>>>(bufOb, Wob, bufX, bufHb,
        x_T, tl2w, tl2b, 256, 256,256, F_RES, 0,0,0,0);
  // 6. fused FFN1: TO = relu(h2@w1^T+b1)@w2^T + b2 + x
  FfnArgs fa1;
  fa1.A=bufHb; fa1.W1=f1w1b; fa1.B1=f1b1; fa1.W2=f1w2b; fa1.B2=f1b2;
  fa1.resid=bufX; fa1.outF=bufTO; fa1.outB=bufTOb;
  ffn<<<256,512,0,stream>>>(fa1);
  // 7. x2 = TO @ sw[b]^T + TO ; h3 = LN(x2)
  gemm_ln<<<dim3(16,1,16),512,0,stream>>>(bufTOb, swB, bufX2, bufHb,
        bufTO, flw, flb, 256, 256,256, F_RES,
        131072, 65536, 131072, 131072);
  // 8. fused FFN2: out = relu(h3@w1^T+b1)@w2^T + b2 + x2 -> fp32 d_out
  FfnArgs fa2;
  fa2.A=bufHb; fa2.W1=f2w1b; fa2.B1=f2b1; fa2.W2=f2w2b; fa2.B2=f2b2;
  fa2.resid=bufX2; fa2.outF=out0; fa2.outB=nullptr;
  ffn<<<256,512,0,stream>>>(fa2);
}

// Round 9
// 285.587 us; speedup vs baseline: 1.7074x; 1.0301x over previous
//
#include <hip/hip_runtime.h>
#include <hip/hip_bf16.h>

typedef __hip_bfloat16 bf16;
typedef __attribute__((ext_vector_type(8))) short short8;
typedef __attribute__((ext_vector_type(4))) float f32x4;

#define F_BIAS 1
#define F_RELU 2
#define F_RES  4

__device__ __forceinline__ void st_out(float* p, float v){ *p = v; }
__device__ __forceinline__ void st_out(bf16* p, float v){ *p = __float2bfloat16(v); }
__device__ __forceinline__ short f2bs(float f){
  bf16 h = __float2bfloat16(f);
  return *reinterpret_cast<short*>(&h);
}

// async global->LDS, 16 B per lane (linear LDS dest, pre-swizzled global src).
__device__ __forceinline__ void gl_lds16(const void* g, void* l){
  __builtin_amdgcn_global_load_lds(
      (const __attribute__((address_space(1))) void*)g,
      (__attribute__((address_space(3))) void*)l, 16, 0, 0);
}

// LDS-only barrier: orders ds ops, leaves global_load_lds (vmcnt) in flight.
__device__ __forceinline__ void lgkm_barrier(){
  asm volatile("s_waitcnt lgkmcnt(0)" ::: "memory");
  __builtin_amdgcn_s_barrier();
}

// ---------------- prologue: weight prep + LN(x_T) + LN(x_S) ----------------
struct ProArgs {
  const float* wsrc[10];
  bf16* wdst[10];
  const float *xT, *xS, *tl1w, *tl1b, *sl1w, *sl1b;
  bf16 *hT, *hS;
};

template<int RL>
__device__ __forceinline__ void wave_ln(bf16* __restrict__ dst,
    const float* __restrict__ src, const float* __restrict__ w,
    const float* __restrict__ bvec, int row){
  int lane = threadIdx.x & 63;
  const float* s = src + (size_t)row*RL;
  float4 v0 = *(const float4*)(s + lane*4);
  float4 v1 = {0.f,0.f,0.f,0.f};
  float sum = v0.x+v0.y+v0.z+v0.w;
  float sq  = v0.x*v0.x+v0.y*v0.y+v0.z*v0.z+v0.w*v0.w;
  if (RL == 512){
    v1 = *(const float4*)(s + 256 + lane*4);
    sum += v1.x+v1.y+v1.z+v1.w;
    sq  += v1.x*v1.x+v1.y*v1.y+v1.z*v1.z+v1.w*v1.w;
  }
  #pragma unroll
  for (int off=32; off; off>>=1){
    sum += __shfl_xor(sum, off, 64);
    sq  += __shfl_xor(sq , off, 64);
  }
  const float inv = 1.0f/(float)RL;
  float mean = sum*inv;
  float rstd = rsqrtf(sq*inv - mean*mean + 1e-6f);
  float4 w0 = *(const float4*)(w + lane*4);
  float4 b0 = *(const float4*)(bvec + lane*4);
  bf16* d = dst + (size_t)row*RL;
  short4 o;
  o.x = f2bs((v0.x-mean)*rstd*w0.x + b0.x);
  o.y = f2bs((v0.y-mean)*rstd*w0.y + b0.y);
  o.z = f2bs((v0.z-mean)*rstd*w0.z + b0.z);
  o.w = f2bs((v0.w-mean)*rstd*w0.w + b0.w);
  *(short4*)((short*)d + lane*4) = o;
  if (RL == 512){
    float4 w1 = *(const float4*)(w + 256 + lane*4);
    float4 b1 = *(const float4*)(bvec + 256 + lane*4);
    short4 o1;
    o1.x = f2bs((v1.x-mean)*rstd*w1.x + b1.x);
    o1.y = f2bs((v1.y-mean)*rstd*w1.y + b1.y);
    o1.z = f2bs((v1.z-mean)*rstd*w1.z + b1.z);
    o1.w = f2bs((v1.w-mean)*rstd*w1.w + b1.w);
    *(short4*)((short*)d + 256 + lane*4) = o1;
  }
}

__global__ __launch_bounds__(256) void prologue(ProArgs a){
  int blk = blockIdx.x;
  int wid = threadIdx.x >> 6;
  if (blk < 1792){
    int v = blk*256 + threadIdx.x;
    int e = v*4;
    int seg = (e>=65536)+(e>=131072)+(e>=196608)+(e>=262144)+(e>=524288)
            + (e>=786432)+(e>=1048576)+(e>=1310720)+(e>=1572864);
    const int starts[10] = {0,65536,131072,196608,262144,524288,786432,
                            1048576,1310720,1572864};
    int off = e - starts[seg];
    float4 f = *(const float4*)(a.wsrc[seg] + off);
    short4 o;
    o.x = f2bs(f.x); o.y = f2bs(f.y); o.z = f2bs(f.z); o.w = f2bs(f.w);
    *(short4*)((short*)a.wdst[seg] + off) = o;
  } else if (blk < 1792 + 2048){
    wave_ln<256>(a.hT, a.xT, a.tl1w, a.tl1b, (blk-1792)*4 + wid);
  } else {
    wave_ln<512>(a.hS, a.xS, a.sl1w, a.sl1b, (blk-3840)*4 + wid);
  }
}

// -- MFMA bf16 GEMM body (256 thr): dbuf, barrier at TOP ---------------------
template<int BM, int BN, int BK>
__device__ __forceinline__ void gemm_body(
    short* __restrict__ AsB, short* __restrict__ BsB,
    const bf16* __restrict__ A, const bf16* __restrict__ B,
    float* __restrict__ outF, bf16* __restrict__ outB,
    const float* __restrict__ bias, const float* __restrict__ resid,
    int K, int lda, int ldb, int ldc, int flags, int m0, int n0){
  int tid = threadIdx.x;
  int w = tid>>6, lane = tid&63, quad = lane>>4, l16 = lane&15;
  constexpr int MF  = BM/32;
  constexpr int NF  = BN/32;
  constexpr int CPR = BK/8;
  constexpr int CA  = BM*CPR/256;
  constexpr int CB  = BN*CPR/256;
  int wm = (w>>1)*(BM/2), wn = (w&1)*(BN/2);
  f32x4 acc[MF][NF];
  #pragma unroll
  for (int r=0;r<MF;r++)
    #pragma unroll
    for (int j=0;j<NF;j++)
      acc[r][j] = (f32x4){0.f,0.f,0.f,0.f};

  auto stage = [&](int k0, int half){
    short* as = AsB + half*(BM*BK);
    short* bs = BsB + half*(BN*BK);
    #pragma unroll
    for (int c=0;c<CA;c++){
      int ch = tid + c*256;
      int row = ch / CPR, p = ch % CPR;
      gl_lds16(A + (size_t)(m0+row)*lda + k0 + ((p ^ (row&(CPR-1)))*8),
               &as[row*BK + p*8]);
    }
    #pragma unroll
    for (int c=0;c<CB;c++){
      int ch = tid + c*256;
      int row = ch / CPR, p = ch % CPR;
      gl_lds16(B + (size_t)(n0+row)*ldb + k0 + ((p ^ (row&(CPR-1)))*8),
               &bs[row*BK + p*8]);
    }
  };

  stage(0, 0);
  int nk = K / BK;
  for (int t = 0; t < nk; ++t){
    __syncthreads();
    if (t+1 < nk) stage((t+1)*BK, (t+1)&1);
    const short* as = AsB + (t&1)*(BM*BK);
    const short* bs = BsB + (t&1)*(BN*BK);
    #pragma unroll
    for (int ks=0; ks<BK/32; ++ks){
      short8 af[MF], bfr[NF];
      #pragma unroll
      for (int r=0;r<MF;r++){
        int rr = wm + r*16 + l16;
        af[r] = *(short8*)&as[rr*BK + (((ks*4+quad) ^ (rr&(CPR-1)))*8)];
      }
      #pragma unroll
      for (int j=0;j<NF;j++){
        int rr = wn + j*16 + l16;
        bfr[j] = *(short8*)&bs[rr*BK + (((ks*4+quad) ^ (rr&(CPR-1)))*8)];
      }
      #pragma unroll
      for (int r=0;r<MF;r++)
        #pragma unroll
        for (int j=0;j<NF;j++)
          acc[r][j] = __builtin_amdgcn_mfma_f32_16x16x32_bf16(af[r], bfr[j], acc[r][j], 0,0,0);
    }
  }
  #pragma unroll
  for (int r=0;r<MF;r++){
    int mb = m0 + wm + r*16 + quad*4;
    #pragma unroll
    for (int j=0;j<NF;j++){
      int n = n0 + wn + j*16 + l16;
      float bv = (flags & F_BIAS) ? bias[n] : 0.0f;
      #pragma unroll
      for (int e=0;e<4;e++){
        float v = acc[r][j][e] + bv;
        if (flags & F_RELU) v = fmaxf(v, 0.0f);
        long long idx = (long long)(mb+e)*ldc + n;
        if (flags & F_RES) v += resid[idx];
        if (outF) outF[idx] = v;
        if (outB) st_out(outB + idx, v);
      }
    }
  }
}

// ---- dual GEMM: two independent <128,128> GEMMs in one launch (1-D grid) ---
struct GArgs {
  const bf16 *A, *B;
  float* outF; bf16* outB;
  const float *bias, *resid;
  int K, lda, ldb, ldc, flags, ty;
};
__global__ __launch_bounds__(256) void gemm_dual(GArgs g0, GArgs g1, int n0){
  __shared__ __align__(16) short As[2*128*64];
  __shared__ __align__(16) short Bs[2*128*64];
  int id = blockIdx.x;
  bool first = id < n0;
  const GArgs& g = first ? g0 : g1;
  int t = first ? id : id - n0;
  int bx = t / g.ty, by = t - bx*g.ty;
  gemm_body<128,128,64>(As, Bs, g.A, g.B, g.outF, g.outB, g.bias, g.resid,
                        g.K, g.lda, g.ldb, g.ldc, g.flags, bx*128, by*128);
}

// ---- lnffn: x = A@Bm^T + resid ; h = LN(x) ; out = relu(h@W1^T+b1)@W2^T + b2 + x
// x carried in REGISTERS; h never leaves LDS. 512 thr, BM=32, 144 KB LDS.
struct LnFfnArgs {
  const bf16 *A;        // [*,256] bf16 GEMM A
  const bf16 *Bm;       // [256,256] bf16 GEMM B (Wo or sw[b])
  const float *resid0;  // f32 resid for x
  const float *lnw, *lnb;
  const bf16 *W1; const float *B1;   // [1024,256], [1024]
  const bf16 *W2; const float *B2;   // [256,1024], [256]
  float *outF; bf16 *outB;
  long long sA, sB, sR, sO;          // per-blockIdx.z element strides
};

__global__ __launch_bounds__(512) void lnffn(LnFfnArgs a){
  __shared__ __align__(16) short arena[73728];   // 144 KB, time-phased
  __shared__ float redS[4][32], redQ[4][32];
  int bz = blockIdx.z;
  const bf16* A  = a.A  + (size_t)bz*a.sA;
  const bf16* Bm = a.Bm + (size_t)bz*a.sB;
  long long rbase = (long long)bz*a.sR;
  long long obase = (long long)bz*a.sO;
  int tid = threadIdx.x;
  int w = tid>>6, lane = tid&63, quad = lane>>4, l16 = lane&15;
  int m0 = blockIdx.x*32;
  int wm = (w>>2)*16;        // 0/16
  int wn = (w&3)*64;         // 0/64/128/192

  short* As  = arena;            // [0..4096)       phase 0
  short* Bs  = arena + 4096;     // [4096..36864)   phase 0
  short* Hin = arena;            // [0..8192)       h tile (after phase 0)
  short* Hs  = arena + 8192;     // [8192..40960)   hidden 32x1024
  short* Bst = arena + 40960;    // [40960..73728)  dbuf W stage

  // ---------------- phase 0: GEMM (K=256) + resid + LN -> Hin --------------
  f32x4 acc[4];
  #pragma unroll
  for (int j=0;j<4;j++) acc[j] = (f32x4){0.f,0.f,0.f,0.f};

  auto stage0 = [&](int k0, int half){
    short* as = As + half*(32*64);
    short* bs = Bs + half*(256*64);
    if (tid < 256){
      int row = tid >> 3, p = tid & 7;
      gl_lds16(A + (size_t)(m0+row)*256 + k0 + ((p ^ (row&7))*8),
               &as[row*64 + p*8]);
    }
    #pragma unroll
    for (int c=0;c<4;c++){
      int ch = tid + c*512;
      int row = ch >> 3, p = ch & 7;
      gl_lds16(Bm + (size_t)row*256 + k0 + ((p ^ (row&7))*8),
               &bs[row*64 + p*8]);
    }
  };

  stage0(0, 0);
  for (int t = 0; t < 4; ++t){
    __syncthreads();
    if (t+1 < 4) stage0((t+1)*64, (t+1)&1);
    const short* as = As + (t&1)*(32*64);
    const short* bs = Bs + (t&1)*(256*64);
    #pragma unroll
    for (int ks=0; ks<2; ++ks){
      int rr = wm + l16;
      short8 af = *(short8*)&as[rr*64 + (((ks*4+quad) ^ (rr&7))*8)];
      #pragma unroll
      for (int j=0;j<4;j++){
        int rb = wn + j*16 + l16;
        short8 bfr = *(short8*)&bs[rb*64 + (((ks*4+quad) ^ (rb&7))*8)];
        acc[j] = __builtin_amdgcn_mfma_f32_16x16x32_bf16(af, bfr, acc[j], 0,0,0);
      }
    }
  }
  #pragma unroll
  for (int e=0;e<4;e++){
    int row = wm + quad*4 + e;
    float s = 0.f, q2 = 0.f;
    #pragma unroll
    for (int j=0;j<4;j++){
      float v = acc[j][e] + a.resid0[rbase + (long long)(m0+row)*256 + wn + j*16 + l16];
      acc[j][e] = v;                     // x stays in registers
      s += v; q2 += v*v;
    }
    #pragma unroll
    for (int off=1; off<16; off<<=1){
      s  += __shfl_xor(s , off, 16);
      q2 += __shfl_xor(q2, off, 16);
    }
    if (l16==0){ redS[w&3][row] = s; redQ[w&3][row] = q2; }
  }
  __syncthreads();                       // all K-loop LDS reads done; As/Bs dead
  #pragma unroll
  for (int e=0;e<4;e++){
    int row = wm + quad*4 + e;
    float tot = redS[0][row] + redS[1][row] + redS[2][row] + redS[3][row];
    float tq  = redQ[0][row] + redQ[1][row] + redQ[2][row] + redQ[3][row];
    float mean = tot * (1.0f/256.0f);
    float var  = tq * (1.0f/256.0f) - mean*mean;
    float rstd = rsqrtf(var + 1e-6f);
    #pragma unroll
    for (int j=0;j<4;j++){
      int col = wn + j*16 + l16;
      float h = (acc[j][e]-mean)*rstd*a.lnw[col] + a.lnb[col];
      int g = col >> 3;
      Hin[row*256 + ((g ^ row)*8) + (col&7)] = f2bs(h);   // phase-A XOR layout
    }
  }

  // ---------------- phase A: H = relu(h @ W1^T + b1) -> Hs -----------------
  auto stageA = [&](int i, int half){
    short* bs = Bst + half*16384;
    int nc = i>>2, kt = i&3;
    #pragma unroll
    for (int c=0;c<2;c++){
      int ch = tid + c*512;
      int row = ch>>3, p = ch&7;
      gl_lds16(a.W1 + (size_t)(nc*128+row)*256 + kt*64 + ((p ^ (row&7))*8),
               &bs[ch*8]);
    }
  };
  stageA(0, 0);
  f32x4 a2[2];
  for (int i=0; i<32; ++i){
    __syncthreads();                     // drains stage i (+Hin writes at i=0)
    if (i+1 < 32) stageA(i+1, (i+1)&1);
    const short* bs = Bst + (i&1)*16384;
    int kt = i&3, nc = i>>2;
    if (kt==0){
      a2[0] = (f32x4){0.f,0.f,0.f,0.f};
      a2[1] = (f32x4){0.f,0.f,0.f,0.f};
    }
    #pragma unroll
    for (int ks=0; ks<2; ++ks){
      int rr = wm + l16;
      int kk = kt*8 + ks*4 + quad;
      short8 af = *(short8*)&Hin[rr*256 + ((kk ^ rr)*8)];
      #pragma unroll
      for (int j=0;j<2;j++){
        int rb = (w&3)*32 + j*16 + l16;
        short8 bk = *(short8*)&bs[rb*64 + (((ks*4+quad) ^ (rb&7))*8)];
        a2[j] = __builtin_amdgcn_mfma_f32_16x16x32_bf16(af, bk, a2[j], 0,0,0);
      }
    }
    if (kt==3){
      #pragma unroll
      for (int j=0;j<2;j++)
        #pragma unroll
        for (int e=0;e<4;e++){
          int row = wm + quad*4 + e;
          int col = nc*128 + (w&3)*32 + j*16 + l16;
          float v = fmaxf(a2[j][e] + a.B1[col], 0.0f);
          int g = col>>3;
          Hs[row*1024 + ((g ^ (row&7))*8) + (col&7)] = f2bs(v);
        }
    }
  }

  // ---------------- phase B: out = H @ W2^T + b2 + x -----------------------
  auto stageB = [&](int kt, int half){
    short* bs = Bst + half*16384;
    #pragma unroll
    for (int c=0;c<4;c++){
      int ch = tid + c*512;
      int row = ch>>3, p = ch&7;
      gl_lds16(a.W2 + (size_t)row*1024 + kt*64 + ((p ^ (row&7))*8),
               &bs[ch*8]);
    }
  };
  stageB(0, 0);                          // half0 free (last read at i=30)
  f32x4 accB[4];
  #pragma unroll
  for (int j=0;j<4;j++) accB[j] = (f32x4){0.f,0.f,0.f,0.f};
  for (int kt=0; kt<16; ++kt){
    __syncthreads();                     // drains stage kt (+Hs writes at kt=0)
    if (kt+1 < 16) stageB(kt+1, (kt+1)&1);
    const short* bs = Bst + (kt&1)*16384;
    #pragma unroll
    for (int ks=0; ks<2; ++ks){
      int rr = wm + l16;
      int kk = kt*8 + ks*4 + quad;
      short8 af = *(short8*)&Hs[rr*1024 + ((kk ^ (rr&7))*8)];
      #pragma unroll
      for (int j=0;j<4;j++){
        int rb = wn + j*16 + l16;
        short8 bk = *(short8*)&bs[rb*64 + (((ks*4+quad) ^ (rb&7))*8)];
        accB[j] = __builtin_amdgcn_mfma_f32_16x16x32_bf16(af, bk, accB[j], 0,0,0);
      }
    }
  }
  #pragma unroll
  for (int j=0;j<4;j++){
    int n = wn + j*16 + l16;
    float bv = a.B2[n];
    #pragma unroll
    for (int e=0;e<4;e++){
      int row = wm + quad*4 + e;
      long long idx = obase + (long long)(m0+row)*256 + n;
      float v = accB[j][e] + bv + acc[j][e];   // register-carried x
      a.outF[idx] = v;
      if (a.outB) st_out(a.outB + idx, v);
    }
  }
}

// ---------------- MFMA flash temporal causal attention ----------------
__device__ __forceinline__ int fsw(int row){ return (row>>1)&3; }
__global__ __launch_bounds__(256) void flash_mfma(
    const bf16* __restrict__ qkv, bf16* __restrict__ o){
  int qt = (int)gridDim.x - 1 - (int)blockIdx.x;   // longest blocks first
  int h = blockIdx.y, b = blockIdx.z;
  int tid = threadIdx.x;
  int w = tid>>6, lane = tid&63, quad = lane>>4, l16 = lane&15;
  __shared__ __align__(16) bf16 Qs[64*32];
  __shared__ __align__(16) bf16 Ks[2][64*32];
  __shared__ __align__(16) bf16 Vt[2][32*72];
  __shared__ __align__(16) bf16 Ps[64*72];
  const bf16* base = qkv + (size_t)b*512*768;
  int t0 = qt*64;
  int srow = tid>>2, spos = tid&3;
  gl_lds16(base + (size_t)(t0+srow)*768 + h*32 + ((spos ^ fsw(srow))*8),
           &Qs[srow*32 + spos*8]);
  {
    const bf16* rp = base + (size_t)srow*768 + h*32;
    gl_lds16(rp + 256 + ((spos ^ fsw(srow))*8), &Ks[0][srow*32 + spos*8]);
    short8 v = *(const short8*)(rp + 512 + spos*8);
    #pragma unroll
    for (int q=0;q<8;q++){
      short tmp = v[q];
      Vt[0][(spos*8+q)*72 + srow] = *(bf16*)&tmp;
    }
  }
  f32x4 accO[2];
  accO[0] = (f32x4){0.f,0.f,0.f,0.f};
  accO[1] = (f32x4){0.f,0.f,0.f,0.f};
  float m_i[4], l_i[4];
  #pragma unroll
  for (int e=0;e<4;e++){ m_i[e] = -3.0e38f; l_i[e] = 0.0f; }
  const float scale = 0.17677669529663687f;
  __syncthreads();
  int rq = w*16 + l16;
  short8 aq = *(short8*)&Qs[rq*32 + ((quad ^ fsw(rq))*8)];

  for (int kt = 0; kt <= qt; ++kt){
    if (kt) __syncthreads();
    int cur = kt&1, nxt = cur^1;
    bool pre = (kt < qt);
    short8 vpre;
    if (pre){
      const bf16* rp = base + (size_t)((kt+1)*64 + srow)*768 + h*32;
      gl_lds16(rp + 256 + ((spos ^ fsw(srow))*8), &Ks[nxt][srow*32 + spos*8]);
      vpre = *(const short8*)(rp + 512 + spos*8);
    }
    f32x4 S[4];
    #pragma unroll
    for (int j2=0;j2<4;j2++){
      int rk = j2*16 + l16;
      short8 bk = *(short8*)&Ks[cur][rk*32 + ((quad ^ fsw(rk))*8)];
      S[j2] = __builtin_amdgcn_mfma_f32_16x16x32_bf16(aq, bk,
                (f32x4){0.f,0.f,0.f,0.f}, 0,0,0);
    }
    bool diag = (kt == qt);
    int s0 = kt*64;
    int qrow_base = t0 + w*16 + quad*4;
    #pragma unroll
    for (int e=0;e<4;e++){
      float sv[4];
      #pragma unroll
      for (int j2=0;j2<4;j2++){
        float x = S[j2][e]*scale;
        if (diag && (s0 + j2*16 + l16 > qrow_base + e)) x = -3.0e38f;
        sv[j2] = x;
      }
      float mx = fmaxf(fmaxf(sv[0],sv[1]), fmaxf(sv[2],sv[3]));
      #pragma unroll
      for (int off=1; off<16; off<<=1) mx = fmaxf(mx, __shfl_xor(mx, off, 64));
      float m_new = fmaxf(m_i[e], mx);
      float alpha = __expf(m_i[e]-m_new);
      float rs = 0.0f;
      #pragma unroll
      for (int j2=0;j2<4;j2++){
        float p = __expf(sv[j2]-m_new);
        rs += p;
        Ps[(w*16+quad*4+e)*72 + j2*16 + l16] = __float2bfloat16(p);
      }
      #pragma unroll
      for (int off=1; off<16; off<<=1) rs += __shfl_xor(rs, off, 64);
      l_i[e] = l_i[e]*alpha + rs;
      m_i[e] = m_new;
      accO[0][e] *= alpha;
      accO[1][e] *= alpha;
    }
    asm volatile("s_waitcnt lgkmcnt(0)" ::: "memory");
    __builtin_amdgcn_sched_barrier(0);
    #pragma unroll
    for (int sh=0; sh<2; ++sh){
      short8 ap = *(short8*)&Ps[(w*16+l16)*72 + sh*32 + quad*8];
      #pragma unroll
      for (int dh=0; dh<2; ++dh){
        short8 bv = *(short8*)&Vt[cur][(dh*16+l16)*72 + sh*32 + quad*8];
        accO[dh] = __builtin_amdgcn_mfma_f32_16x16x32_bf16(ap, bv, accO[dh], 0,0,0);
      }
    }
    if (pre){
      #pragma unroll
      for (int q=0;q<8;q++){
        short tmp = vpre[q];
        Vt[nxt][(spos*8+q)*72 + srow] = *(bf16*)&tmp;
      }
    }
  }
  #pragma unroll
  for (int e=0;e<4;e++){
    float inv = 1.0f/l_i[e];
    int t = t0 + w*16 + quad*4 + e;
    bf16* op = o + ((size_t)(b*512+t))*256 + h*32 + l16;
    op[0]  = __float2bfloat16(accO[0][e]*inv);
    op[16] = __float2bfloat16(accO[1][e]*inv);
  }
}

// ------- standalone fused spatial attention (full-K dbuf, 256 thr) ---------
__global__ __launch_bounds__(256) void spatial_fused(
    const bf16* __restrict__ qk, float* __restrict__ out1,
    bf16* __restrict__ swB){
  int ct = blockIdx.x & 15, b = blockIdx.x >> 4;
  int tid = threadIdx.x;
  int w = tid>>6, lane = tid&63, quad = lane>>4, l16 = lane&15;
  __shared__ __align__(16) bf16 Qall[16*512];
  __shared__ __align__(16) bf16 Ks[2][256*64];
  __shared__ float redM[4][16], redS2[4][16];
  const bf16* qbase = qk + ((size_t)(b*256 + ct*16))*1024;
  #pragma unroll
  for (int c=0;c<4;c++){
    int ch = tid + c*256;
    int row = ch>>6, p = ch&63;
    gl_lds16(qbase + (size_t)row*1024 + ((p ^ (row&7))*8), &Qall[row*512 + p*8]);
  }
  auto stageK = [&](int h, int half){
    bf16* ks = Ks[half];
    #pragma unroll
    for (int c=0;c<8;c++){
      int ch = tid + c*256;
      int e = ch>>3, p = ch&7;
      gl_lds16(qk + ((size_t)(b*256 + e))*1024 + 512 + h*64 + ((p ^ (e&7))*8),
               &ks[e*64 + p*8]);
    }
  };
  stageK(0, 0);
  float fRes[4][4];
  #pragma unroll
  for (int j=0;j<4;j++)
    #pragma unroll
    for (int e=0;e<4;e++) fRes[j][e] = 0.0f;

  for (int h=0; h<8; ++h){
    __syncthreads();
    if (h+1 < 8) stageK(h+1, (h+1)&1);
    const bf16* kcur = Ks[h&1];
    f32x4 acc[4];
    #pragma unroll
    for (int j=0;j<4;j++) acc[j] = (f32x4){0.f,0.f,0.f,0.f};
    #pragma unroll
    for (int ki=0; ki<2; ++ki){
      int g = h*8 + ki*4 + quad;
      short8 aq = *(short8*)&Qall[l16*512 + ((g ^ (l16&7))*8)];
      #pragma unroll
      for (int j=0;j<4;j++){
        int e = w*64 + j*16 + l16;
        short8 bk = *(short8*)&kcur[e*64 + (((ki*4+quad) ^ (e&7))*8)];
        acc[j] = __builtin_amdgcn_mfma_f32_16x16x32_bf16(aq, bk, acc[j], 0,0,0);
      }
    }
    #pragma unroll
    for (int e=0;e<4;e++){
      float m = -3.0e38f;
      #pragma unroll
      for (int j=0;j<4;j++){
        float s = acc[j][e]*0.125f;
        acc[j][e] = s;
        m = fmaxf(m, s);
      }
      #pragma unroll
      for (int off=1; off<16; off<<=1) m = fmaxf(m, __shfl_xor(m, off, 16));
      if (l16==0) redM[w][quad*4+e] = m;
    }
    lgkm_barrier();
    #pragma unroll
    for (int e=0;e<4;e++){
      int r = quad*4+e;
      float m = fmaxf(fmaxf(redM[0][r],redM[1][r]), fmaxf(redM[2][r],redM[3][r]));
      float s = 0.0f;
      #pragma unroll
      for (int j=0;j<4;j++){
        float p = __expf(acc[j][e]-m);
        acc[j][e] = p; s += p;
      }
      #pragma unroll
      for (int off=1; off<16; off<<=1) s += __shfl_xor(s, off, 16);
      if (l16==0) redS2[w][r] = s;
    }
    lgkm_barrier();
    #pragma unroll
    for (int e=0;e<4;e++){
      int r = quad*4+e;
      float tot = redS2[0][r]+redS2[1][r]+redS2[2][r]+redS2[3][r];
      float inv = 0.125f/tot;
      #pragma unroll
      for (int j=0;j<4;j++) fRes[j][e] += acc[j][e]*inv;
    }
  }
  #pragma unroll
  for (int e=0;e<4;e++){
    int c = ct*16 + quad*4 + e;
    size_t rb = ((size_t)b*256 + c)*256;
    #pragma unroll
    for (int j=0;j<4;j++){
      int col = w*64 + j*16 + l16;
      out1[rb+col] = fRes[j][e];
      swB[rb+col]  = __float2bfloat16(fRes[j][e]);
    }
  }
}

extern "C" void kernel_launch(void* const* d_in, const int* in_sizes, int n_in,
                              void* d_out, int out_size, void* d_ws, size_t ws_size,
                              hipStream_t stream){
  (void)in_sizes; (void)n_in; (void)out_size; (void)ws_size;
  const float* x_T  = (const float*)d_in[0];
  const float* x_S  = (const float*)d_in[1];
  const float* Wq_t = (const float*)d_in[2];
  const float* Wk_t = (const float*)d_in[3];
  const float* Wv_t = (const float*)d_in[4];
  const float* Wo   = (const float*)d_in[5];
  const float* Wq_s = (const float*)d_in[6];
  const float* Wk_s = (const float*)d_in[7];
  const float* f1w1 = (const float*)d_in[8];
  const float* f1b1 = (const float*)d_in[9];
  const float* f1w2 = (const float*)d_in[10];
  const float* f1b2 = (const float*)d_in[11];
  const float* f2w1 = (const float*)d_in[12];
  const float* f2b1 = (const float*)d_in[13];
  const float* f2w2 = (const float*)d_in[14];
  const float* f2b2 = (const float*)d_in[15];
  const float* tl1w = (const float*)d_in[16];
  const float* tl1b = (const float*)d_in[17];
  const float* tl2w = (const float*)d_in[18];
  const float* tl2b = (const float*)d_in[19];
  const float* sl1w = (const float*)d_in[20];
  const float* sl1b = (const float*)d_in[21];
  const float* flw  = (const float*)d_in[22];
  const float* flb  = (const float*)d_in[23];

  float* ws = (float*)d_ws;
  size_t off = 0;
  bf16*  Wqkvb  = (bf16*)(ws + off); off += 768*256/2;
  bf16*  Wob    = (bf16*)(ws + off); off += 256*256/2;
  bf16*  f1w1b  = (bf16*)(ws + off); off += 1024*256/2;
  bf16*  f1w2b  = (bf16*)(ws + off); off += 256*1024/2;
  bf16*  f2w1b  = (bf16*)(ws + off); off += 1024*256/2;
  bf16*  f2w2b  = (bf16*)(ws + off); off += 256*1024/2;
  bf16*  WSb    = (bf16*)(ws + off); off += 1024*512/2;
  bf16*  bufHb  = (bf16*)(ws + off); off += (size_t)8192*256/2;
  bf16*  bufHSb = (bf16*)(ws + off); off += (size_t)4096*512/2;
  bf16*  bufQKVb= (bf16*)(ws + off); off += (size_t)8192*768/2;
  bf16*  bufOb  = (bf16*)(ws + off); off += (size_t)8192*256/2;
  bf16*  bufTOb = (bf16*)(ws + off); off += (size_t)8192*256/2;
  bf16*  swB    = (bf16*)(ws + off); off += (size_t)16*256*256/2;
  bf16*  qkB    = (bf16*)(ws + off); off += (size_t)4096*1024/2;
  float* bufTO  = ws + off; off += (size_t)8192*256;

  float* out0 = (float*)d_out;                      // [B,T,C]
  float* out1 = out0 + (size_t)16*512*256;          // spatial_weights [B,C,C]

  // 1. prologue: weight prep + LN(x_T) + LN(x_S)
  ProArgs pa;
  pa.wsrc[0]=Wq_t;  pa.wdst[0]=Wqkvb;
  pa.wsrc[1]=Wk_t;  pa.wdst[1]=Wqkvb+65536;
  pa.wsrc[2]=Wv_t;  pa.wdst[2]=Wqkvb+131072;
  pa.wsrc[3]=Wo;    pa.wdst[3]=Wob;
  pa.wsrc[4]=f1w1;  pa.wdst[4]=f1w1b;
  pa.wsrc[5]=f1w2;  pa.wdst[5]=f1w2b;
  pa.wsrc[6]=f2w1;  pa.wdst[6]=f2w1b;
  pa.wsrc[7]=f2w2;  pa.wdst[7]=f2w2b;
  pa.wsrc[8]=Wq_s;  pa.wdst[8]=WSb;
  pa.wsrc[9]=Wk_s;  pa.wdst[9]=WSb+262144;
  pa.xT=x_T; pa.xS=x_S; pa.tl1w=tl1w; pa.tl1b=tl1b;
  pa.sl1w=sl1w; pa.sl1b=sl1b; pa.hT=bufHb; pa.hS=bufHSb;
  prologue<<<4864,256,0,stream>>>(pa);

  // 2. dual <128,128>: qkv (384 tiles) + spatial projection (256 tiles)
  GArgs gq, gs;
  gq.A=bufHb;  gq.B=Wqkvb; gq.outF=nullptr; gq.outB=bufQKVb;
  gq.bias=nullptr; gq.resid=nullptr;
  gq.K=256; gq.lda=256; gq.ldb=256; gq.ldc=768; gq.flags=0; gq.ty=6;
  gs.A=bufHSb; gs.B=WSb;   gs.outF=nullptr; gs.outB=qkB;
  gs.bias=nullptr; gs.resid=nullptr;
  gs.K=512; gs.lda=512; gs.ldb=512; gs.ldc=1024; gs.flags=0; gs.ty=8;
  gemm_dual<<<640,256,0,stream>>>(gq, gs, 384);

  // 3. fused spatial attention (qkB L2-hot)
  spatial_fused<<<256,256,0,stream>>>(qkB, out1, swB);

  // 4. temporal causal flash attention -> bf16 o
  flash_mfma<<<dim3(8,8,16),256,0,stream>>>(bufQKVb, bufOb);

  // 5. lnffn1: x = o@Wo^T + x_T ; h2 = LN(x) ; TO = relu(h2@w1^T+b1)@w2^T + b2 + x
  LnFfnArgs la1;
  la1.A=bufOb; la1.Bm=Wob; la1.resid0=x_T; la1.lnw=tl2w; la1.lnb=tl2b;
  la1.W1=f1w1b; la1.B1=f1b1; la1.W2=f1w2b; la1.B2=f1b2;
  la1.outF=bufTO; la1.outB=bufTOb;
  la1.sA=0; la1.sB=0; la1.sR=0; la1.sO=0;
  lnffn<<<dim3(256,1,1),512,0,stream>>>(la1);

  // 6. lnffn2: x2 = TO@sw[b]^T + TO ; h3 = LN(x2) ; out = relu(h3@w1+b1)@w2 + b2 + x2
  LnFfnArgs la2;
  la2.A=bufTOb; la2.Bm=swB; la2.resid0=bufTO; la2.lnw=flw; la2.lnb=flb;
  la2.W1=f2w1b; la2.B1=f2b1; la2.W2=f2w2b; la2.B2=f2b2;
  la2.outF=out0; la2.outB=nullptr;
  la2.sA=131072; la2.sB=65536; la2.sR=131072; la2.sO=131072;
  lnffn<<<dim3(16,1,16),512,0,stream>>>(la2);
}

// Round 10
// 284.851 us; speedup vs baseline: 1.7118x; 1.0026x over previous
//
#include <hip/hip_runtime.h>
#include <hip/hip_bf16.h>

typedef __hip_bfloat16 bf16;
typedef __attribute__((ext_vector_type(8))) short short8;
typedef __attribute__((ext_vector_type(4))) float f32x4;

#define F_BIAS 1
#define F_RELU 2
#define F_RES  4

__device__ __forceinline__ void st_out(float* p, float v){ *p = v; }
__device__ __forceinline__ void st_out(bf16* p, float v){ *p = __float2bfloat16(v); }
__device__ __forceinline__ short f2bs(float f){
  bf16 h = __float2bfloat16(f);
  return *reinterpret_cast<short*>(&h);
}

// async global->LDS, 16 B per lane (linear LDS dest, pre-swizzled global src).
__device__ __forceinline__ void gl_lds16(const void* g, void* l){
  __builtin_amdgcn_global_load_lds(
      (const __attribute__((address_space(1))) void*)g,
      (__attribute__((address_space(3))) void*)l, 16, 0, 0);
}

// LDS-only barrier: orders ds ops, leaves global_load_lds (vmcnt) in flight.
__device__ __forceinline__ void lgkm_barrier(){
  asm volatile("s_waitcnt lgkmcnt(0)" ::: "memory");
  __builtin_amdgcn_s_barrier();
}

// ---------------- prologue: weight prep + LN(x_T) + LN(x_S) ----------------
struct ProArgs {
  const float* wsrc[10];
  bf16* wdst[10];
  const float *xT, *xS, *tl1w, *tl1b, *sl1w, *sl1b;
  bf16 *hT, *hS;
};

template<int RL>
__device__ __forceinline__ void wave_ln(bf16* __restrict__ dst,
    const float* __restrict__ src, const float* __restrict__ w,
    const float* __restrict__ bvec, int row){
  int lane = threadIdx.x & 63;
  const float* s = src + (size_t)row*RL;
  float4 v0 = *(const float4*)(s + lane*4);
  float4 v1 = {0.f,0.f,0.f,0.f};
  float sum = v0.x+v0.y+v0.z+v0.w;
  float sq  = v0.x*v0.x+v0.y*v0.y+v0.z*v0.z+v0.w*v0.w;
  if (RL == 512){
    v1 = *(const float4*)(s + 256 + lane*4);
    sum += v1.x+v1.y+v1.z+v1.w;
    sq  += v1.x*v1.x+v1.y*v1.y+v1.z*v1.z+v1.w*v1.w;
  }
  #pragma unroll
  for (int off=32; off; off>>=1){
    sum += __shfl_xor(sum, off, 64);
    sq  += __shfl_xor(sq , off, 64);
  }
  const float inv = 1.0f/(float)RL;
  float mean = sum*inv;
  float rstd = rsqrtf(sq*inv - mean*mean + 1e-6f);
  float4 w0 = *(const float4*)(w + lane*4);
  float4 b0 = *(const float4*)(bvec + lane*4);
  bf16* d = dst + (size_t)row*RL;
  short4 o;
  o.x = f2bs((v0.x-mean)*rstd*w0.x + b0.x);
  o.y = f2bs((v0.y-mean)*rstd*w0.y + b0.y);
  o.z = f2bs((v0.z-mean)*rstd*w0.z + b0.z);
  o.w = f2bs((v0.w-mean)*rstd*w0.w + b0.w);
  *(short4*)((short*)d + lane*4) = o;
  if (RL == 512){
    float4 w1 = *(const float4*)(w + 256 + lane*4);
    float4 b1 = *(const float4*)(bvec + 256 + lane*4);
    short4 o1;
    o1.x = f2bs((v1.x-mean)*rstd*w1.x + b1.x);
    o1.y = f2bs((v1.y-mean)*rstd*w1.y + b1.y);
    o1.z = f2bs((v1.z-mean)*rstd*w1.z + b1.z);
    o1.w = f2bs((v1.w-mean)*rstd*w1.w + b1.w);
    *(short4*)((short*)d + 256 + lane*4) = o1;
  }
}

__global__ __launch_bounds__(256) void prologue(ProArgs a){
  int blk = blockIdx.x;
  int wid = threadIdx.x >> 6;
  if (blk < 1792){
    int v = blk*256 + threadIdx.x;
    int e = v*4;
    int seg = (e>=65536)+(e>=131072)+(e>=196608)+(e>=262144)+(e>=524288)
            + (e>=786432)+(e>=1048576)+(e>=1310720)+(e>=1572864);
    const int starts[10] = {0,65536,131072,196608,262144,524288,786432,
                            1048576,1310720,1572864};
    int off = e - starts[seg];
    float4 f = *(const float4*)(a.wsrc[seg] + off);
    short4 o;
    o.x = f2bs(f.x); o.y = f2bs(f.y); o.z = f2bs(f.z); o.w = f2bs(f.w);
    *(short4*)((short*)a.wdst[seg] + off) = o;
  } else if (blk < 1792 + 2048){
    wave_ln<256>(a.hT, a.xT, a.tl1w, a.tl1b, (blk-1792)*4 + wid);
  } else {
    wave_ln<512>(a.hS, a.xS, a.sl1w, a.sl1b, (blk-3840)*4 + wid);
  }
}

// -- MFMA bf16 GEMM body (256 thr): dbuf, barrier at TOP ---------------------
template<int BM, int BN, int BK>
__device__ __forceinline__ void gemm_body(
    short* __restrict__ AsB, short* __restrict__ BsB,
    const bf16* __restrict__ A, const bf16* __restrict__ B,
    float* __restrict__ outF, bf16* __restrict__ outB,
    const float* __restrict__ bias, const float* __restrict__ resid,
    int K, int lda, int ldb, int ldc, int flags, int m0, int n0){
  int tid = threadIdx.x;
  int w = tid>>6, lane = tid&63, quad = lane>>4, l16 = lane&15;
  constexpr int MF  = BM/32;
  constexpr int NF  = BN/32;
  constexpr int CPR = BK/8;
  constexpr int CA  = BM*CPR/256;
  constexpr int CB  = BN*CPR/256;
  int wm = (w>>1)*(BM/2), wn = (w&1)*(BN/2);
  f32x4 acc[MF][NF];
  #pragma unroll
  for (int r=0;r<MF;r++)
    #pragma unroll
    for (int j=0;j<NF;j++)
      acc[r][j] = (f32x4){0.f,0.f,0.f,0.f};

  auto stage = [&](int k0, int half){
    short* as = AsB + half*(BM*BK);
    short* bs = BsB + half*(BN*BK);
    #pragma unroll
    for (int c=0;c<CA;c++){
      int ch = tid + c*256;
      int row = ch / CPR, p = ch % CPR;
      gl_lds16(A + (size_t)(m0+row)*lda + k0 + ((p ^ (row&(CPR-1)))*8),
               &as[row*BK + p*8]);
    }
    #pragma unroll
    for (int c=0;c<CB;c++){
      int ch = tid + c*256;
      int row = ch / CPR, p = ch % CPR;
      gl_lds16(B + (size_t)(n0+row)*ldb + k0 + ((p ^ (row&(CPR-1)))*8),
               &bs[row*BK + p*8]);
    }
  };

  stage(0, 0);
  int nk = K / BK;
  for (int t = 0; t < nk; ++t){
    __syncthreads();
    if (t+1 < nk) stage((t+1)*BK, (t+1)&1);
    const short* as = AsB + (t&1)*(BM*BK);
    const short* bs = BsB + (t&1)*(BN*BK);
    #pragma unroll
    for (int ks=0; ks<BK/32; ++ks){
      short8 af[MF], bfr[NF];
      #pragma unroll
      for (int r=0;r<MF;r++){
        int rr = wm + r*16 + l16;
        af[r] = *(short8*)&as[rr*BK + (((ks*4+quad) ^ (rr&(CPR-1)))*8)];
      }
      #pragma unroll
      for (int j=0;j<NF;j++){
        int rr = wn + j*16 + l16;
        bfr[j] = *(short8*)&bs[rr*BK + (((ks*4+quad) ^ (rr&(CPR-1)))*8)];
      }
      #pragma unroll
      for (int r=0;r<MF;r++)
        #pragma unroll
        for (int j=0;j<NF;j++)
          acc[r][j] = __builtin_amdgcn_mfma_f32_16x16x32_bf16(af[r], bfr[j], acc[r][j], 0,0,0);
    }
  }
  #pragma unroll
  for (int r=0;r<MF;r++){
    int mb = m0 + wm + r*16 + quad*4;
    #pragma unroll
    for (int j=0;j<NF;j++){
      int n = n0 + wn + j*16 + l16;
      float bv = (flags & F_BIAS) ? bias[n] : 0.0f;
      #pragma unroll
      for (int e=0;e<4;e++){
        float v = acc[r][j][e] + bv;
        if (flags & F_RELU) v = fmaxf(v, 0.0f);
        long long idx = (long long)(mb+e)*ldc + n;
        if (flags & F_RES) v += resid[idx];
        if (outF) outF[idx] = v;
        if (outB) st_out(outB + idx, v);
      }
    }
  }
}

// ---- dual GEMM: two independent <128,128> GEMMs in one launch (1-D grid) ---
struct GArgs {
  const bf16 *A, *B;
  float* outF; bf16* outB;
  const float *bias, *resid;
  int K, lda, ldb, ldc, flags, ty;
};
__global__ __launch_bounds__(256) void gemm_dual(GArgs g0, GArgs g1, int n0){
  __shared__ __align__(16) short As[2*128*64];
  __shared__ __align__(16) short Bs[2*128*64];
  int id = blockIdx.x;
  bool first = id < n0;
  const GArgs& g = first ? g0 : g1;
  int t = first ? id : id - n0;
  int bx = t / g.ty, by = t - bx*g.ty;
  gemm_body<128,128,64>(As, Bs, g.A, g.B, g.outF, g.outB, g.bias, g.resid,
                        g.K, g.lda, g.ldb, g.ldc, g.flags, bx*128, by*128);
}

// ---- lnffn v2: x = A@Bm^T + resid ; h = LN(x) ; out = relu(h@W1^T+b1)@W2^T + b2 + x
// Weight B-fragments loaded DIRECTLY from global (L2-hot; no LDS staging, no
// K-loop barriers). Only Hin/Hs in LDS (80 KB). x register-carried. 512 thr.
struct LnFfnArgs {
  const bf16 *A;        // [*,256] bf16 GEMM A
  const bf16 *Bm;       // [256,256] bf16 GEMM B (Wo or sw[b])
  const float *resid0;  // f32 resid for x
  const float *lnw, *lnb;
  const bf16 *W1; const float *B1;   // [1024,256], [1024]
  const bf16 *W2; const float *B2;   // [256,1024], [256]
  float *outF; bf16 *outB;
  long long sA, sB, sR, sO;          // per-blockIdx.z element strides
};

__global__ __launch_bounds__(512) void lnffn(LnFfnArgs a){
  __shared__ __align__(16) short Hin[32*256];    // 16 KB (XOR g^row)
  __shared__ __align__(16) short Hs[32*1024];    // 64 KB (XOR g^(row&7))
  // LN reduction scratch overlays the (not-yet-written) head of Hs.
  float (*redS)[32] = (float(*)[32])Hs;          // [8][32] = 1 KB
  float (*redQ)[32] = (float(*)[32])(Hs + 512);  // [8][32] = 1 KB
  int bz = blockIdx.z;
  const bf16* A  = a.A  + (size_t)bz*a.sA;
  const bf16* Bm = a.Bm + (size_t)bz*a.sB;
  long long rbase = (long long)bz*a.sR;
  long long obase = (long long)bz*a.sO;
  int tid = threadIdx.x;
  int w = tid>>6, lane = tid&63, quad = lane>>4, l16 = lane&15;
  int m0 = blockIdx.x*32;

  // ------ phase 0: x = A@Bm^T (K=256), all fragments direct from global ----
  // Wave layout 1M x 8N: rows 0..31 (MF=2), cols w*32..w*32+32 (NF=2).
  f32x4 acc0[2][2];
  #pragma unroll
  for (int r=0;r<2;r++)
    #pragma unroll
    for (int j=0;j<2;j++) acc0[r][j] = (f32x4){0.f,0.f,0.f,0.f};
  #pragma unroll
  for (int ks=0; ks<8; ++ks){
    short8 af[2], bk[2];
    #pragma unroll
    for (int r=0;r<2;r++)
      af[r] = *(const short8*)(A + (size_t)(m0 + r*16 + l16)*256 + ks*32 + quad*8);
    #pragma unroll
    for (int j=0;j<2;j++)
      bk[j] = *(const short8*)(Bm + (size_t)(w*32 + j*16 + l16)*256 + ks*32 + quad*8);
    #pragma unroll
    for (int r=0;r<2;r++)
      #pragma unroll
      for (int j=0;j<2;j++)
        acc0[r][j] = __builtin_amdgcn_mfma_f32_16x16x32_bf16(af[r], bk[j], acc0[r][j], 0,0,0);
  }
  // resid add + per-row LN statistics
  #pragma unroll
  for (int r=0;r<2;r++)
    #pragma unroll
    for (int e=0;e<4;e++){
      int row = r*16 + quad*4 + e;
      float s = 0.f, q2 = 0.f;
      #pragma unroll
      for (int j=0;j<2;j++){
        float v = acc0[r][j][e] +
                  a.resid0[rbase + (long long)(m0+row)*256 + w*32 + j*16 + l16];
        acc0[r][j][e] = v;               // x stays in registers
        s += v; q2 += v*v;
      }
      #pragma unroll
      for (int off=1; off<16; off<<=1){
        s  += __shfl_xor(s , off, 16);
        q2 += __shfl_xor(q2, off, 16);
      }
      if (l16==0){ redS[w][row] = s; redQ[w][row] = q2; }
    }
  __syncthreads();
  #pragma unroll
  for (int r=0;r<2;r++)
    #pragma unroll
    for (int e=0;e<4;e++){
      int row = r*16 + quad*4 + e;
      float tot = 0.f, tq = 0.f;
      #pragma unroll
      for (int ww=0; ww<8; ww++){ tot += redS[ww][row]; tq += redQ[ww][row]; }
      float mean = tot * (1.0f/256.0f);
      float var  = tq * (1.0f/256.0f) - mean*mean;
      float rstd = rsqrtf(var + 1e-6f);
      #pragma unroll
      for (int j=0;j<2;j++){
        int col = w*32 + j*16 + l16;
        float h = (acc0[r][j][e]-mean)*rstd*a.lnw[col] + a.lnb[col];
        int g = col >> 3;
        Hin[row*256 + ((g ^ row)*8) + (col&7)] = f2bs(h);
      }
    }
  __syncthreads();                       // Hin visible; redS region now dead

  // ------ phase A: H = relu(h@W1^T + b1) -> Hs; W1 frags direct global -----
  // 2 hidden chunks of 64 cols/wave (acc 32 VGPR); no barriers in K-loop.
  for (int hc=0; hc<2; ++hc){
    f32x4 acc1[2][4];
    #pragma unroll
    for (int r=0;r<2;r++)
      #pragma unroll
      for (int j=0;j<4;j++) acc1[r][j] = (f32x4){0.f,0.f,0.f,0.f};
    #pragma unroll
    for (int ks=0; ks<8; ++ks){
      short8 af[2], bk[4];
      #pragma unroll
      for (int r=0;r<2;r++){
        int rr = r*16 + l16;
        int kk = ks*4 + quad;
        af[r] = *(short8*)&Hin[rr*256 + ((kk ^ rr)*8)];
      }
      #pragma unroll
      for (int j=0;j<4;j++){
        int hr = w*128 + hc*64 + j*16 + l16;
        bk[j] = *(const short8*)(a.W1 + (size_t)hr*256 + ks*32 + quad*8);
      }
      #pragma unroll
      for (int r=0;r<2;r++)
        #pragma unroll
        for (int j=0;j<4;j++)
          acc1[r][j] = __builtin_amdgcn_mfma_f32_16x16x32_bf16(af[r], bk[j], acc1[r][j], 0,0,0);
    }
    #pragma unroll
    for (int r=0;r<2;r++)
      #pragma unroll
      for (int j=0;j<4;j++)
        #pragma unroll
        for (int e=0;e<4;e++){
          int row = r*16 + quad*4 + e;
          int col = w*128 + hc*64 + j*16 + l16;
          float v = fmaxf(acc1[r][j][e] + a.B1[col], 0.0f);
          int g = col>>3;
          Hs[row*1024 + ((g ^ (row&7))*8) + (col&7)] = f2bs(v);
        }
  }
  __syncthreads();                       // Hs visible to all waves

  // ------ phase B: out = H@W2^T + b2 + x; W2 frags direct global -----------
  f32x4 accB[2][2];
  #pragma unroll
  for (int r=0;r<2;r++)
    #pragma unroll
    for (int j=0;j<2;j++) accB[r][j] = (f32x4){0.f,0.f,0.f,0.f};
  #pragma unroll 8
  for (int ks=0; ks<32; ++ks){
    short8 af[2], bk[2];
    #pragma unroll
    for (int r=0;r<2;r++){
      int rr = r*16 + l16;
      int kk = ks*4 + quad;
      af[r] = *(short8*)&Hs[rr*1024 + ((kk ^ (rr&7))*8)];
    }
    #pragma unroll
    for (int j=0;j<2;j++){
      int n = w*32 + j*16 + l16;
      bk[j] = *(const short8*)(a.W2 + (size_t)n*1024 + ks*32 + quad*8);
    }
    #pragma unroll
    for (int r=0;r<2;r++)
      #pragma unroll
      for (int j=0;j<2;j++)
        accB[r][j] = __builtin_amdgcn_mfma_f32_16x16x32_bf16(af[r], bk[j], accB[r][j], 0,0,0);
  }
  #pragma unroll
  for (int r=0;r<2;r++)
    #pragma unroll
    for (int j=0;j<2;j++){
      int n = w*32 + j*16 + l16;
      float bv = a.B2[n];
      #pragma unroll
      for (int e=0;e<4;e++){
        int row = r*16 + quad*4 + e;
        long long idx = obase + (long long)(m0+row)*256 + n;
        float v = accB[r][j][e] + bv + acc0[r][j][e];   // register-carried x
        a.outF[idx] = v;
        if (a.outB) st_out(a.outB + idx, v);
      }
    }
}

// ---------------- MFMA flash temporal causal attention ----------------
__device__ __forceinline__ int fsw(int row){ return (row>>1)&3; }
__global__ __launch_bounds__(256) void flash_mfma(
    const bf16* __restrict__ qkv, bf16* __restrict__ o){
  int qt = (int)gridDim.x - 1 - (int)blockIdx.x;   // longest blocks first
  int h = blockIdx.y, b = blockIdx.z;
  int tid = threadIdx.x;
  int w = tid>>6, lane = tid&63, quad = lane>>4, l16 = lane&15;
  __shared__ __align__(16) bf16 Qs[64*32];
  __shared__ __align__(16) bf16 Ks[2][64*32];
  __shared__ __align__(16) bf16 Vt[2][32*72];
  __shared__ __align__(16) bf16 Ps[64*72];
  const bf16* base = qkv + (size_t)b*512*768;
  int t0 = qt*64;
  int srow = tid>>2, spos = tid&3;
  gl_lds16(base + (size_t)(t0+srow)*768 + h*32 + ((spos ^ fsw(srow))*8),
           &Qs[srow*32 + spos*8]);
  {
    const bf16* rp = base + (size_t)srow*768 + h*32;
    gl_lds16(rp + 256 + ((spos ^ fsw(srow))*8), &Ks[0][srow*32 + spos*8]);
    short8 v = *(const short8*)(rp + 512 + spos*8);
    #pragma unroll
    for (int q=0;q<8;q++){
      short tmp = v[q];
      Vt[0][(spos*8+q)*72 + srow] = *(bf16*)&tmp;
    }
  }
  f32x4 accO[2];
  accO[0] = (f32x4){0.f,0.f,0.f,0.f};
  accO[1] = (f32x4){0.f,0.f,0.f,0.f};
  float m_i[4], l_i[4];
  #pragma unroll
  for (int e=0;e<4;e++){ m_i[e] = -3.0e38f; l_i[e] = 0.0f; }
  const float scale = 0.17677669529663687f;
  __syncthreads();
  int rq = w*16 + l16;
  short8 aq = *(short8*)&Qs[rq*32 + ((quad ^ fsw(rq))*8)];

  for (int kt = 0; kt <= qt; ++kt){
    if (kt) __syncthreads();
    int cur = kt&1, nxt = cur^1;
    bool pre = (kt < qt);
    short8 vpre;
    if (pre){
      const bf16* rp = base + (size_t)((kt+1)*64 + srow)*768 + h*32;
      gl_lds16(rp + 256 + ((spos ^ fsw(srow))*8), &Ks[nxt][srow*32 + spos*8]);
      vpre = *(const short8*)(rp + 512 + spos*8);
    }
    f32x4 S[4];
    #pragma unroll
    for (int j2=0;j2<4;j2++){
      int rk = j2*16 + l16;
      short8 bk = *(short8*)&Ks[cur][rk*32 + ((quad ^ fsw(rk))*8)];
      S[j2] = __builtin_amdgcn_mfma_f32_16x16x32_bf16(aq, bk,
                (f32x4){0.f,0.f,0.f,0.f}, 0,0,0);
    }
    bool diag = (kt == qt);
    int s0 = kt*64;
    int qrow_base = t0 + w*16 + quad*4;
    #pragma unroll
    for (int e=0;e<4;e++){
      float sv[4];
      #pragma unroll
      for (int j2=0;j2<4;j2++){
        float x = S[j2][e]*scale;
        if (diag && (s0 + j2*16 + l16 > qrow_base + e)) x = -3.0e38f;
        sv[j2] = x;
      }
      float mx = fmaxf(fmaxf(sv[0],sv[1]), fmaxf(sv[2],sv[3]));
      #pragma unroll
      for (int off=1; off<16; off<<=1) mx = fmaxf(mx, __shfl_xor(mx, off, 64));
      float m_new = fmaxf(m_i[e], mx);
      float alpha = __expf(m_i[e]-m_new);
      float rs = 0.0f;
      #pragma unroll
      for (int j2=0;j2<4;j2++){
        float p = __expf(sv[j2]-m_new);
        rs += p;
        Ps[(w*16+quad*4+e)*72 + j2*16 + l16] = __float2bfloat16(p);
      }
      #pragma unroll
      for (int off=1; off<16; off<<=1) rs += __shfl_xor(rs, off, 64);
      l_i[e] = l_i[e]*alpha + rs;
      m_i[e] = m_new;
      accO[0][e] *= alpha;
      accO[1][e] *= alpha;
    }
    asm volatile("s_waitcnt lgkmcnt(0)" ::: "memory");
    __builtin_amdgcn_sched_barrier(0);
    #pragma unroll
    for (int sh=0; sh<2; ++sh){
      short8 ap = *(short8*)&Ps[(w*16+l16)*72 + sh*32 + quad*8];
      #pragma unroll
      for (int dh=0; dh<2; ++dh){
        short8 bv = *(short8*)&Vt[cur][(dh*16+l16)*72 + sh*32 + quad*8];
        accO[dh] = __builtin_amdgcn_mfma_f32_16x16x32_bf16(ap, bv, accO[dh], 0,0,0);
      }
    }
    if (pre){
      #pragma unroll
      for (int q=0;q<8;q++){
        short tmp = vpre[q];
        Vt[nxt][(spos*8+q)*72 + srow] = *(bf16*)&tmp;
      }
    }
  }
  #pragma unroll
  for (int e=0;e<4;e++){
    float inv = 1.0f/l_i[e];
    int t = t0 + w*16 + quad*4 + e;
    bf16* op = o + ((size_t)(b*512+t))*256 + h*32 + l16;
    op[0]  = __float2bfloat16(accO[0][e]*inv);
    op[16] = __float2bfloat16(accO[1][e]*inv);
  }
}

// ------- standalone fused spatial attention (full-K dbuf, 256 thr) ---------
__global__ __launch_bounds__(256) void spatial_fused(
    const bf16* __restrict__ qk, float* __restrict__ out1,
    bf16* __restrict__ swB){
  int ct = blockIdx.x & 15, b = blockIdx.x >> 4;
  int tid = threadIdx.x;
  int w = tid>>6, lane = tid&63, quad = lane>>4, l16 = lane&15;
  __shared__ __align__(16) bf16 Qall[16*512];
  __shared__ __align__(16) bf16 Ks[2][256*64];
  __shared__ float redM[4][16], redS2[4][16];
  const bf16* qbase = qk + ((size_t)(b*256 + ct*16))*1024;
  #pragma unroll
  for (int c=0;c<4;c++){
    int ch = tid + c*256;
    int row = ch>>6, p = ch&63;
    gl_lds16(qbase + (size_t)row*1024 + ((p ^ (row&7))*8), &Qall[row*512 + p*8]);
  }
  auto stageK = [&](int h, int half){
    bf16* ks = Ks[half];
    #pragma unroll
    for (int c=0;c<8;c++){
      int ch = tid + c*256;
      int e = ch>>3, p = ch&7;
      gl_lds16(qk + ((size_t)(b*256 + e))*1024 + 512 + h*64 + ((p ^ (e&7))*8),
               &ks[e*64 + p*8]);
    }
  };
  stageK(0, 0);
  float fRes[4][4];
  #pragma unroll
  for (int j=0;j<4;j++)
    #pragma unroll
    for (int e=0;e<4;e++) fRes[j][e] = 0.0f;

  for (int h=0; h<8; ++h){
    __syncthreads();
    if (h+1 < 8) stageK(h+1, (h+1)&1);
    const bf16* kcur = Ks[h&1];
    f32x4 acc[4];
    #pragma unroll
    for (int j=0;j<4;j++) acc[j] = (f32x4){0.f,0.f,0.f,0.f};
    #pragma unroll
    for (int ki=0; ki<2; ++ki){
      int g = h*8 + ki*4 + quad;
      short8 aq = *(short8*)&Qall[l16*512 + ((g ^ (l16&7))*8)];
      #pragma unroll
      for (int j=0;j<4;j++){
        int e = w*64 + j*16 + l16;
        short8 bk = *(short8*)&kcur[e*64 + (((ki*4+quad) ^ (e&7))*8)];
        acc[j] = __builtin_amdgcn_mfma_f32_16x16x32_bf16(aq, bk, acc[j], 0,0,0);
      }
    }
    #pragma unroll
    for (int e=0;e<4;e++){
      float m = -3.0e38f;
      #pragma unroll
      for (int j=0;j<4;j++){
        float s = acc[j][e]*0.125f;
        acc[j][e] = s;
        m = fmaxf(m, s);
      }
      #pragma unroll
      for (int off=1; off<16; off<<=1) m = fmaxf(m, __shfl_xor(m, off, 16));
      if (l16==0) redM[w][quad*4+e] = m;
    }
    lgkm_barrier();
    #pragma unroll
    for (int e=0;e<4;e++){
      int r = quad*4+e;
      float m = fmaxf(fmaxf(redM[0][r],redM[1][r]), fmaxf(redM[2][r],redM[3][r]));
      float s = 0.0f;
      #pragma unroll
      for (int j=0;j<4;j++){
        float p = __expf(acc[j][e]-m);
        acc[j][e] = p; s += p;
      }
      #pragma unroll
      for (int off=1; off<16; off<<=1) s += __shfl_xor(s, off, 16);
      if (l16==0) redS2[w][r] = s;
    }
    lgkm_barrier();
    #pragma unroll
    for (int e=0;e<4;e++){
      int r = quad*4+e;
      float tot = redS2[0][r]+redS2[1][r]+redS2[2][r]+redS2[3][r];
      float inv = 0.125f/tot;
      #pragma unroll
      for (int j=0;j<4;j++) fRes[j][e] += acc[j][e]*inv;
    }
  }
  #pragma unroll
  for (int e=0;e<4;e++){
    int c = ct*16 + quad*4 + e;
    size_t rb = ((size_t)b*256 + c)*256;
    #pragma unroll
    for (int j=0;j<4;j++){
      int col = w*64 + j*16 + l16;
      out1[rb+col] = fRes[j][e];
      swB[rb+col]  = __float2bfloat16(fRes[j][e]);
    }
  }
}

extern "C" void kernel_launch(void* const* d_in, const int* in_sizes, int n_in,
                              void* d_out, int out_size, void* d_ws, size_t ws_size,
                              hipStream_t stream){
  (void)in_sizes; (void)n_in; (void)out_size; (void)ws_size;
  const float* x_T  = (const float*)d_in[0];
  const float* x_S  = (const float*)d_in[1];
  const float* Wq_t = (const float*)d_in[2];
  const float* Wk_t = (const float*)d_in[3];
  const float* Wv_t = (const float*)d_in[4];
  const float* Wo   = (const float*)d_in[5];
  const float* Wq_s = (const float*)d_in[6];
  const float* Wk_s = (const float*)d_in[7];
  const float* f1w1 = (const float*)d_in[8];
  const float* f1b1 = (const float*)d_in[9];
  const float* f1w2 = (const float*)d_in[10];
  const float* f1b2 = (const float*)d_in[11];
  const float* f2w1 = (const float*)d_in[12];
  const float* f2b1 = (const float*)d_in[13];
  const float* f2w2 = (const float*)d_in[14];
  const float* f2b2 = (const float*)d_in[15];
  const float* tl1w = (const float*)d_in[16];
  const float* tl1b = (const float*)d_in[17];
  const float* tl2w = (const float*)d_in[18];
  const float* tl2b = (const float*)d_in[19];
  const float* sl1w = (const float*)d_in[20];
  const float* sl1b = (const float*)d_in[21];
  const float* flw  = (const float*)d_in[22];
  const float* flb  = (const float*)d_in[23];

  float* ws = (float*)d_ws;
  size_t off = 0;
  bf16*  Wqkvb  = (bf16*)(ws + off); off += 768*256/2;
  bf16*  Wob    = (bf16*)(ws + off); off += 256*256/2;
  bf16*  f1w1b  = (bf16*)(ws + off); off += 1024*256/2;
  bf16*  f1w2b  = (bf16*)(ws + off); off += 256*1024/2;
  bf16*  f2w1b  = (bf16*)(ws + off); off += 1024*256/2;
  bf16*  f2w2b  = (bf16*)(ws + off); off += 256*1024/2;
  bf16*  WSb    = (bf16*)(ws + off); off += 1024*512/2;
  bf16*  bufHb  = (bf16*)(ws + off); off += (size_t)8192*256/2;
  bf16*  bufHSb = (bf16*)(ws + off); off += (size_t)4096*512/2;
  bf16*  bufQKVb= (bf16*)(ws + off); off += (size_t)8192*768/2;
  bf16*  bufOb  = (bf16*)(ws + off); off += (size_t)8192*256/2;
  bf16*  bufTOb = (bf16*)(ws + off); off += (size_t)8192*256/2;
  bf16*  swB    = (bf16*)(ws + off); off += (size_t)16*256*256/2;
  bf16*  qkB    = (bf16*)(ws + off); off += (size_t)4096*1024/2;
  float* bufTO  = ws + off; off += (size_t)8192*256;

  float* out0 = (float*)d_out;                      // [B,T,C]
  float* out1 = out0 + (size_t)16*512*256;          // spatial_weights [B,C,C]

  // 1. prologue: weight prep + LN(x_T) + LN(x_S)
  ProArgs pa;
  pa.wsrc[0]=Wq_t;  pa.wdst[0]=Wqkvb;
  pa.wsrc[1]=Wk_t;  pa.wdst[1]=Wqkvb+65536;
  pa.wsrc[2]=Wv_t;  pa.wdst[2]=Wqkvb+131072;
  pa.wsrc[3]=Wo;    pa.wdst[3]=Wob;
  pa.wsrc[4]=f1w1;  pa.wdst[4]=f1w1b;
  pa.wsrc[5]=f1w2;  pa.wdst[5]=f1w2b;
  pa.wsrc[6]=f2w1;  pa.wdst[6]=f2w1b;
  pa.wsrc[7]=f2w2;  pa.wdst[7]=f2w2b;
  pa.wsrc[8]=Wq_s;  pa.wdst[8]=WSb;
  pa.wsrc[9]=Wk_s;  pa.wdst[9]=WSb+262144;
  pa.xT=x_T; pa.xS=x_S; pa.tl1w=tl1w; pa.tl1b=tl1b;
  pa.sl1w=sl1w; pa.sl1b=sl1b; pa.hT=bufHb; pa.hS=bufHSb;
  prologue<<<4864,256,0,stream>>>(pa);

  // 2. dual <128,128>: qkv (384 tiles) + spatial projection (256 tiles)
  GArgs gq, gs;
  gq.A=bufHb;  gq.B=Wqkvb; gq.outF=nullptr; gq.outB=bufQKVb;
  gq.bias=nullptr; gq.resid=nullptr;
  gq.K=256; gq.lda=256; gq.ldb=256; gq.ldc=768; gq.flags=0; gq.ty=6;
  gs.A=bufHSb; gs.B=WSb;   gs.outF=nullptr; gs.outB=qkB;
  gs.bias=nullptr; gs.resid=nullptr;
  gs.K=512; gs.lda=512; gs.ldb=512; gs.ldc=1024; gs.flags=0; gs.ty=8;
  gemm_dual<<<640,256,0,stream>>>(gq, gs, 384);

  // 3. fused spatial attention (qkB L2-hot)
  spatial_fused<<<256,256,0,stream>>>(qkB, out1, swB);

  // 4. temporal causal flash attention -> bf16 o
  flash_mfma<<<dim3(8,8,16),256,0,stream>>>(bufQKVb, bufOb);

  // 5. lnffn1: x = o@Wo^T + x_T ; h2 = LN(x) ; TO = relu(h2@w1^T+b1)@w2^T + b2 + x
  LnFfnArgs la1;
  la1.A=bufOb; la1.Bm=Wob; la1.resid0=x_T; la1.lnw=tl2w; la1.lnb=tl2b;
  la1.W1=f1w1b; la1.B1=f1b1; la1.W2=f1w2b; la1.B2=f1b2;
  la1.outF=bufTO; la1.outB=bufTOb;
  la1.sA=0; la1.sB=0; la1.sR=0; la1.sO=0;
  lnffn<<<dim3(256,1,1),512,0,stream>>>(la1);

  // 6. lnffn2: x2 = TO@sw[b]^T + TO ; h3 = LN(x2) ; out = relu(h3@w1+b1)@w2 + b2 + x2
  LnFfnArgs la2;
  la2.A=bufTOb; la2.Bm=swB; la2.resid0=bufTO; la2.lnw=flw; la2.lnb=flb;
  la2.W1=f2w1b; la2.B1=f2b1; la2.W2=f2w2b; la2.B2=f2b2;
  la2.outF=out0; la2.outB=nullptr;
  la2.sA=131072; la2.sB=65536; la2.sR=131072; la2.sO=131072;
  lnffn<<<dim3(16,1,16),512,0,stream>>>(la2);
}